// Round 2
// baseline (17201.353 us; speedup 1.0000x reference)
//
#include <hip/hip_runtime.h>
#include <hip/hip_bf16.h>
#include <math.h>

#define EDIM   1024
#define TSEQ   512
#define NBATCH 2
#define NHEAD  16
#define HDIM   64
#define NLAYER 24
#define VOCAB  8124
#define DFFDIM 2730
#define DPAD   2752              // 43*64, padded SwiGLU width
#define MTOK   (NBATCH*TSEQ)     // 1024 rows
#define NELEM  (MTOK*EDIM)       // 1048576
#define EPSF   1e-5f
#define SCALEF (1.0f/32.0f)      // 1/sqrt(emb_dim)
#define NEGBIG (-1e30f)

typedef __bf16 bf16x8 __attribute__((ext_vector_type(8)));
typedef float  f32x4  __attribute__((ext_vector_type(4)));

#define MFMA(a, b, c) __builtin_amdgcn_mfma_f32_16x16x32_bf16((a), (b), (c), 0, 0, 0)

// ---------------------------------------------------------------- embedding+PE
__global__ __launch_bounds__(256) void k_embed(const int* __restrict__ tok,
                                               const float* __restrict__ emb,
                                               float* __restrict__ x) {
  const int bt = blockIdx.x;
  const int t  = bt & (TSEQ - 1);
  const int tk = tok[bt];
  const float* er = emb + (size_t)tk * EDIM;
  float* xr = x + (size_t)bt * EDIM;
  for (int e = threadIdx.x * 4; e < EDIM; e += 256 * 4) {
    float4 v = *(const float4*)(er + e);
    float vv[4] = {v.x, v.y, v.z, v.w};
    float ou[4];
#pragma unroll
    for (int j = 0; j < 4; ++j) {
      int ee = e + j;
      int i2 = ee & ~1;
      float freq = expf(-(float)i2 * (9.210340371976184f / 1024.0f));
      float ang  = (float)t * freq;
      ou[j] = vv[j] + ((ee & 1) ? cosf(ang) : sinf(ang));
    }
    *(float4*)(xr + e) = make_float4(ou[0], ou[1], ou[2], ou[3]);
  }
}

// ---------------------------------------------------------------- global RMS
__global__ __launch_bounds__(256) void k_red1(const float* __restrict__ xin,
                                              float* __restrict__ part) {
  float s = 0.f;
  for (int i = (blockIdx.x * 256 + threadIdx.x) * 4; i < NELEM; i += 256 * 256 * 4) {
    float4 v = *(const float4*)(xin + i);
    s += v.x * v.x + v.y * v.y + v.z * v.z + v.w * v.w;
  }
#pragma unroll
  for (int o = 32; o > 0; o >>= 1) s += __shfl_down(s, o);
  __shared__ float sm[4];
  if ((threadIdx.x & 63) == 0) sm[threadIdx.x >> 6] = s;
  __syncthreads();
  if (threadIdx.x == 0) part[blockIdx.x] = sm[0] + sm[1] + sm[2] + sm[3];
}

__global__ __launch_bounds__(256) void k_red2(const float* __restrict__ part,
                                              float* __restrict__ scale) {
  float s = part[threadIdx.x];
#pragma unroll
  for (int o = 32; o > 0; o >>= 1) s += __shfl_down(s, o);
  __shared__ float sm[4];
  if ((threadIdx.x & 63) == 0) sm[threadIdx.x >> 6] = s;
  __syncthreads();
  if (threadIdx.x == 0) {
    float tot = sm[0] + sm[1] + sm[2] + sm[3];
    scale[0] = 1.0f / sqrtf(tot / (float)NELEM + EPSF);
  }
}

__global__ __launch_bounds__(256) void k_rms(const float* __restrict__ xin,
                                             const float* __restrict__ g,
                                             const float* __restrict__ scale,
                                             float* __restrict__ yout) {
  const float sc = scale[0];
  const int i = (blockIdx.x * 256 + threadIdx.x) * 4;
  float4 v  = *(const float4*)(xin + i);
  float4 gv = *(const float4*)(g + (i & (EDIM - 1)));
  float4 r;
  r.x = v.x * sc * gv.x; r.y = v.y * sc * gv.y;
  r.z = v.z * sc * gv.z; r.w = v.w * sc * gv.w;
  *(float4*)(yout + i) = r;
}

// ================================================================ MFMA GEMMs
// Common structure: 64x64 tile, BK=64, 256 thr = 4 waves, wave tile 32x32
// (2x2 fragments of 16x16x32 bf16 MFMA). LDS tiles stored as [kblk][idx^kblk][8]
// bf16 (XOR swizzle: conflict-free staging writes AND frag reads).
// A frag: row=lane&15, k=(lane>>4)*8+i.  B frag: col=lane&15, same k.
// C/D:   col=lane&15, row=(lane>>4)*4+j.   [verified layout, learn_hip m89/m91]

// ---- generic: out[M=1024,N] = A[1024,K] @ W[K(real),N] + bias (+res)
template <int RES>
__global__ __launch_bounds__(256) void mm_g(const float* __restrict__ A,
                                            const float* __restrict__ W,
                                            const float* __restrict__ bias,
                                            const float* __restrict__ res,
                                            float* __restrict__ out,
                                            int N, int K, int Kreal) {
  __shared__ __align__(16) __bf16 As[8][64][8];
  __shared__ __align__(16) __bf16 Bs[8][64][8];
  const int tid = threadIdx.x, lane = tid & 63, wave = tid >> 6;
  const int m0 = blockIdx.y << 6, n0 = blockIdx.x << 6;
  const int wm = (wave >> 1) << 5, wn = (wave & 1) << 5;
  const int lr = lane & 15, kh = lane >> 4;
  const int ar0 = tid >> 3, akb = tid & 7;
  const int bn = tid & 63, bkb0 = tid >> 6;
  const bool bok = (n0 + bn) < N;
  f32x4 acc00 = {0,0,0,0}, acc01 = {0,0,0,0}, acc10 = {0,0,0,0}, acc11 = {0,0,0,0};

  for (int k0 = 0; k0 < K; k0 += 64) {
#pragma unroll
    for (int r = 0; r < 2; ++r) {
      const int row = ar0 + r * 32;
      const float* ap = A + (size_t)(m0 + row) * K + k0 + akb * 8;
      float4 v0 = *(const float4*)ap, v1 = *(const float4*)(ap + 4);
      bf16x8 w = {(__bf16)v0.x, (__bf16)v0.y, (__bf16)v0.z, (__bf16)v0.w,
                  (__bf16)v1.x, (__bf16)v1.y, (__bf16)v1.z, (__bf16)v1.w};
      *(bf16x8*)&As[akb][row ^ akb][0] = w;
    }
#pragma unroll
    for (int r = 0; r < 2; ++r) {
      const int kb = bkb0 + r * 4;
      float f[8];
#pragma unroll
      for (int i = 0; i < 8; ++i) {
        const int k = k0 + kb * 8 + i;
        f[i] = (bok && k < Kreal) ? W[(size_t)k * N + n0 + bn] : 0.f;
      }
      bf16x8 w = {(__bf16)f[0], (__bf16)f[1], (__bf16)f[2], (__bf16)f[3],
                  (__bf16)f[4], (__bf16)f[5], (__bf16)f[6], (__bf16)f[7]};
      *(bf16x8*)&Bs[kb][bn ^ kb][0] = w;
    }
    __syncthreads();
#pragma unroll
    for (int ks = 0; ks < 2; ++ks) {
      const int kidx = ks * 4 + kh;
      bf16x8 a0 = *(const bf16x8*)&As[kidx][(wm + lr) ^ kidx][0];
      bf16x8 a1 = *(const bf16x8*)&As[kidx][(wm + 16 + lr) ^ kidx][0];
      bf16x8 b0 = *(const bf16x8*)&Bs[kidx][(wn + lr) ^ kidx][0];
      bf16x8 b1 = *(const bf16x8*)&Bs[kidx][(wn + 16 + lr) ^ kidx][0];
      acc00 = MFMA(a0, b0, acc00);
      acc01 = MFMA(a0, b1, acc01);
      acc10 = MFMA(a1, b0, acc10);
      acc11 = MFMA(a1, b1, acc11);
    }
    __syncthreads();
  }
#pragma unroll
  for (int mi = 0; mi < 2; ++mi)
#pragma unroll
    for (int ni = 0; ni < 2; ++ni) {
      f32x4 c = (mi == 0) ? (ni == 0 ? acc00 : acc01) : (ni == 0 ? acc10 : acc11);
      const int col = n0 + wn + ni * 16 + lr;
      if (col < N) {
        const float bs = bias[col];
#pragma unroll
        for (int j = 0; j < 4; ++j) {
          const int row = m0 + wm + mi * 16 + (kh << 2) + j;
          float v = c[j] + bs;
          if (RES) v += res[(size_t)row * N + col];
          out[(size_t)row * N + col] = v;
        }
      }
    }
}

// ---- QKV GEMM (N=3072, K=1024) with q/k/v scatter epilogue
__global__ __launch_bounds__(256) void mm_qkv(const float* __restrict__ A,
                                              const float* __restrict__ W,
                                              const float* __restrict__ bias,
                                              float* __restrict__ qb,
                                              float* __restrict__ kb,
                                              float* __restrict__ vb) {
  const int N = 3 * EDIM, K = EDIM;
  __shared__ __align__(16) __bf16 As[8][64][8];
  __shared__ __align__(16) __bf16 Bs[8][64][8];
  const int tid = threadIdx.x, lane = tid & 63, wave = tid >> 6;
  const int m0 = blockIdx.y << 6, n0 = blockIdx.x << 6;
  const int wm = (wave >> 1) << 5, wn = (wave & 1) << 5;
  const int lr = lane & 15, kh = lane >> 4;
  const int ar0 = tid >> 3, akb = tid & 7;
  const int bn = tid & 63, bkb0 = tid >> 6;
  f32x4 acc00 = {0,0,0,0}, acc01 = {0,0,0,0}, acc10 = {0,0,0,0}, acc11 = {0,0,0,0};

  for (int k0 = 0; k0 < K; k0 += 64) {
#pragma unroll
    for (int r = 0; r < 2; ++r) {
      const int row = ar0 + r * 32;
      const float* ap = A + (size_t)(m0 + row) * K + k0 + akb * 8;
      float4 v0 = *(const float4*)ap, v1 = *(const float4*)(ap + 4);
      bf16x8 w = {(__bf16)v0.x, (__bf16)v0.y, (__bf16)v0.z, (__bf16)v0.w,
                  (__bf16)v1.x, (__bf16)v1.y, (__bf16)v1.z, (__bf16)v1.w};
      *(bf16x8*)&As[akb][row ^ akb][0] = w;
    }
#pragma unroll
    for (int r = 0; r < 2; ++r) {
      const int kb2 = bkb0 + r * 4;
      float f[8];
#pragma unroll
      for (int i = 0; i < 8; ++i)
        f[i] = W[(size_t)(k0 + kb2 * 8 + i) * N + n0 + bn];
      bf16x8 w = {(__bf16)f[0], (__bf16)f[1], (__bf16)f[2], (__bf16)f[3],
                  (__bf16)f[4], (__bf16)f[5], (__bf16)f[6], (__bf16)f[7]};
      *(bf16x8*)&Bs[kb2][bn ^ kb2][0] = w;
    }
    __syncthreads();
#pragma unroll
    for (int ks = 0; ks < 2; ++ks) {
      const int kidx = ks * 4 + kh;
      bf16x8 a0 = *(const bf16x8*)&As[kidx][(wm + lr) ^ kidx][0];
      bf16x8 a1 = *(const bf16x8*)&As[kidx][(wm + 16 + lr) ^ kidx][0];
      bf16x8 b0 = *(const bf16x8*)&Bs[kidx][(wn + lr) ^ kidx][0];
      bf16x8 b1 = *(const bf16x8*)&Bs[kidx][(wn + 16 + lr) ^ kidx][0];
      acc00 = MFMA(a0, b0, acc00);
      acc01 = MFMA(a0, b1, acc01);
      acc10 = MFMA(a1, b0, acc10);
      acc11 = MFMA(a1, b1, acc11);
    }
    __syncthreads();
  }
#pragma unroll
  for (int mi = 0; mi < 2; ++mi)
#pragma unroll
    for (int ni = 0; ni < 2; ++ni) {
      f32x4 c = (mi == 0) ? (ni == 0 ? acc00 : acc01) : (ni == 0 ? acc10 : acc11);
      const int col = n0 + wn + ni * 16 + lr;
      const float bs = bias[col];
      const int h = col / (3 * HDIM);
      const int rsel = (col >> 6) % 3;
      const int s = col & (HDIM - 1);
      float* dst = (rsel == 0) ? qb : (rsel == 1) ? kb : vb;
#pragma unroll
      for (int j = 0; j < 4; ++j) {
        const int row = m0 + wm + mi * 16 + (kh << 2) + j;
        const int b = row >> 9, t = row & (TSEQ - 1);
        dst[((size_t)(b * NHEAD + h) * TSEQ + t) * HDIM + s] = c[j] + bs;
      }
    }
}

// ---- fused W1/W3 SwiGLU (N=2730 guarded, out stride DPAD with zero-fill)
__global__ __launch_bounds__(256) void mm_w13(const float* __restrict__ A,
                                              const float* __restrict__ W1,
                                              const float* __restrict__ W3,
                                              const float* __restrict__ b1,
                                              const float* __restrict__ b3,
                                              float* __restrict__ u) {
  const int N = DFFDIM, K = EDIM;
  __shared__ __align__(16) __bf16 As[8][64][8];
  __shared__ __align__(16) __bf16 B1s[8][64][8];
  __shared__ __align__(16) __bf16 B3s[8][64][8];
  const int tid = threadIdx.x, lane = tid & 63, wave = tid >> 6;
  const int m0 = blockIdx.y << 6, n0 = blockIdx.x << 6;
  const int wm = (wave >> 1) << 5, wn = (wave & 1) << 5;
  const int lr = lane & 15, kh = lane >> 4;
  const int ar0 = tid >> 3, akb = tid & 7;
  const int bn = tid & 63, bkb0 = tid >> 6;
  const bool bok = (n0 + bn) < N;
  f32x4 p00 = {0,0,0,0}, p01 = {0,0,0,0}, p10 = {0,0,0,0}, p11 = {0,0,0,0};
  f32x4 q00 = {0,0,0,0}, q01 = {0,0,0,0}, q10 = {0,0,0,0}, q11 = {0,0,0,0};

  for (int k0 = 0; k0 < K; k0 += 64) {
#pragma unroll
    for (int r = 0; r < 2; ++r) {
      const int row = ar0 + r * 32;
      const float* ap = A + (size_t)(m0 + row) * K + k0 + akb * 8;
      float4 v0 = *(const float4*)ap, v1 = *(const float4*)(ap + 4);
      bf16x8 w = {(__bf16)v0.x, (__bf16)v0.y, (__bf16)v0.z, (__bf16)v0.w,
                  (__bf16)v1.x, (__bf16)v1.y, (__bf16)v1.z, (__bf16)v1.w};
      *(bf16x8*)&As[akb][row ^ akb][0] = w;
    }
#pragma unroll
    for (int r = 0; r < 2; ++r) {
      const int kb2 = bkb0 + r * 4;
      float f1[8], f3[8];
#pragma unroll
      for (int i = 0; i < 8; ++i) {
        const size_t off = (size_t)(k0 + kb2 * 8 + i) * N + n0 + bn;
        f1[i] = bok ? W1[off] : 0.f;
        f3[i] = bok ? W3[off] : 0.f;
      }
      bf16x8 w1 = {(__bf16)f1[0], (__bf16)f1[1], (__bf16)f1[2], (__bf16)f1[3],
                   (__bf16)f1[4], (__bf16)f1[5], (__bf16)f1[6], (__bf16)f1[7]};
      bf16x8 w3 = {(__bf16)f3[0], (__bf16)f3[1], (__bf16)f3[2], (__bf16)f3[3],
                   (__bf16)f3[4], (__bf16)f3[5], (__bf16)f3[6], (__bf16)f3[7]};
      *(bf16x8*)&B1s[kb2][bn ^ kb2][0] = w1;
      *(bf16x8*)&B3s[kb2][bn ^ kb2][0] = w3;
    }
    __syncthreads();
#pragma unroll
    for (int ks = 0; ks < 2; ++ks) {
      const int kidx = ks * 4 + kh;
      bf16x8 a0 = *(const bf16x8*)&As[kidx][(wm + lr) ^ kidx][0];
      bf16x8 a1 = *(const bf16x8*)&As[kidx][(wm + 16 + lr) ^ kidx][0];
      bf16x8 c0 = *(const bf16x8*)&B1s[kidx][(wn + lr) ^ kidx][0];
      bf16x8 c1 = *(const bf16x8*)&B1s[kidx][(wn + 16 + lr) ^ kidx][0];
      bf16x8 d0 = *(const bf16x8*)&B3s[kidx][(wn + lr) ^ kidx][0];
      bf16x8 d1 = *(const bf16x8*)&B3s[kidx][(wn + 16 + lr) ^ kidx][0];
      p00 = MFMA(a0, c0, p00); p01 = MFMA(a0, c1, p01);
      p10 = MFMA(a1, c0, p10); p11 = MFMA(a1, c1, p11);
      q00 = MFMA(a0, d0, q00); q01 = MFMA(a0, d1, q01);
      q10 = MFMA(a1, d0, q10); q11 = MFMA(a1, d1, q11);
    }
    __syncthreads();
  }
#pragma unroll
  for (int mi = 0; mi < 2; ++mi)
#pragma unroll
    for (int ni = 0; ni < 2; ++ni) {
      f32x4 c1 = (mi == 0) ? (ni == 0 ? p00 : p01) : (ni == 0 ? p10 : p11);
      f32x4 c3 = (mi == 0) ? (ni == 0 ? q00 : q01) : (ni == 0 ? q10 : q11);
      const int col = n0 + wn + ni * 16 + lr;
      const bool ok = col < N;
      const float bb1 = ok ? b1[col] : 0.f;
      const float bb3 = ok ? b3[col] : 0.f;
#pragma unroll
      for (int j = 0; j < 4; ++j) {
        const int row = m0 + wm + mi * 16 + (kh << 2) + j;
        float v = 0.f;
        if (ok) {
          const float a1v = c1[j] + bb1;
          const float a3v = c3[j] + bb3;
          v = a1v * (1.0f / (1.0f + __expf(-a1v))) * a3v;
        }
        u[(size_t)row * DPAD + col] = v;
      }
    }
}

// ---- attention QK^T: per (b,h) 512x512x64, causal mask + scale
__global__ __launch_bounds__(256) void mm_qk(const float* __restrict__ qb,
                                             const float* __restrict__ kb,
                                             float* __restrict__ sc) {
  const int bh = blockIdx.z;
  const int m0 = blockIdx.y << 6, n0 = blockIdx.x << 6;
  float* sp = sc + (size_t)bh * TSEQ * TSEQ;
  const int tid = threadIdx.x;
  if (n0 > m0 + 63) {  // fully masked tile
    const int rr = tid >> 4, cc = (tid & 15) << 2;
#pragma unroll
    for (int i = 0; i < 4; ++i) {
      float4 nb = make_float4(NEGBIG, NEGBIG, NEGBIG, NEGBIG);
      *(float4*)&sp[(size_t)(m0 + rr + i * 16) * TSEQ + n0 + cc] = nb;
    }
    return;
  }
  const float* qp = qb + (size_t)bh * TSEQ * HDIM;
  const float* kp = kb + (size_t)bh * TSEQ * HDIM;
  __shared__ __align__(16) __bf16 As[8][64][8];
  __shared__ __align__(16) __bf16 Bs[8][64][8];
  const int lane = tid & 63, wave = tid >> 6;
  const int wm = (wave >> 1) << 5, wn = (wave & 1) << 5;
  const int lr = lane & 15, kh = lane >> 4;
  const int ar0 = tid >> 3, akb = tid & 7;
  f32x4 acc00 = {0,0,0,0}, acc01 = {0,0,0,0}, acc10 = {0,0,0,0}, acc11 = {0,0,0,0};
  // single K-step (K = HDIM = 64); both tiles row-contiguous loads
#pragma unroll
  for (int r = 0; r < 2; ++r) {
    const int row = ar0 + r * 32;
    const float* ap = qp + (size_t)(m0 + row) * HDIM + akb * 8;
    const float* bp = kp + (size_t)(n0 + row) * HDIM + akb * 8;
    float4 v0 = *(const float4*)ap, v1 = *(const float4*)(ap + 4);
    float4 u0 = *(const float4*)bp, u1 = *(const float4*)(bp + 4);
    bf16x8 wa = {(__bf16)v0.x, (__bf16)v0.y, (__bf16)v0.z, (__bf16)v0.w,
                 (__bf16)v1.x, (__bf16)v1.y, (__bf16)v1.z, (__bf16)v1.w};
    bf16x8 wb = {(__bf16)u0.x, (__bf16)u0.y, (__bf16)u0.z, (__bf16)u0.w,
                 (__bf16)u1.x, (__bf16)u1.y, (__bf16)u1.z, (__bf16)u1.w};
    *(bf16x8*)&As[akb][row ^ akb][0] = wa;
    *(bf16x8*)&Bs[akb][row ^ akb][0] = wb;
  }
  __syncthreads();
#pragma unroll
  for (int ks = 0; ks < 2; ++ks) {
    const int kidx = ks * 4 + kh;
    bf16x8 a0 = *(const bf16x8*)&As[kidx][(wm + lr) ^ kidx][0];
    bf16x8 a1 = *(const bf16x8*)&As[kidx][(wm + 16 + lr) ^ kidx][0];
    bf16x8 b0 = *(const bf16x8*)&Bs[kidx][(wn + lr) ^ kidx][0];
    bf16x8 b1 = *(const bf16x8*)&Bs[kidx][(wn + 16 + lr) ^ kidx][0];
    acc00 = MFMA(a0, b0, acc00);
    acc01 = MFMA(a0, b1, acc01);
    acc10 = MFMA(a1, b0, acc10);
    acc11 = MFMA(a1, b1, acc11);
  }
#pragma unroll
  for (int mi = 0; mi < 2; ++mi)
#pragma unroll
    for (int ni = 0; ni < 2; ++ni) {
      f32x4 c = (mi == 0) ? (ni == 0 ? acc00 : acc01) : (ni == 0 ? acc10 : acc11);
      const int col = n0 + wn + ni * 16 + lr;
#pragma unroll
      for (int j = 0; j < 4; ++j) {
        const int row = m0 + wm + mi * 16 + (kh << 2) + j;
        sp[(size_t)row * TSEQ + col] = (col <= row) ? c[j] * SCALEF : NEGBIG;
      }
    }
}

// ---------------------------------------------------------------- row softmax
__global__ __launch_bounds__(256) void k_softmax(float* __restrict__ sc) {
  const int row = blockIdx.x * 4 + (threadIdx.x >> 6);
  const int lane = threadIdx.x & 63;
  float* rp = sc + (size_t)row * TSEQ;
  float v[8];
  float mx = NEGBIG;
#pragma unroll
  for (int j = 0; j < 8; ++j) { v[j] = rp[lane + j * 64]; mx = fmaxf(mx, v[j]); }
#pragma unroll
  for (int o = 32; o > 0; o >>= 1) mx = fmaxf(mx, __shfl_xor(mx, o));
  float s = 0.f;
#pragma unroll
  for (int j = 0; j < 8; ++j) { v[j] = __expf(v[j] - mx); s += v[j]; }
#pragma unroll
  for (int o = 32; o > 0; o >>= 1) s += __shfl_xor(s, o);
  const float inv = 1.0f / s;
#pragma unroll
  for (int j = 0; j < 8; ++j) rp[lane + j * 64] = v[j] * inv;
}

// ---- attention P@V: per (b,h) 512x64x(causal K)
__global__ __launch_bounds__(256) void mm_pv(const float* __restrict__ sc,
                                             const float* __restrict__ vb,
                                             float* __restrict__ y2) {
  const int bh = blockIdx.z;
  const int b = bh >> 4, h = bh & 15;
  const float* sp = sc + (size_t)bh * TSEQ * TSEQ;
  const float* vp = vb + (size_t)bh * TSEQ * HDIM;
  __shared__ __align__(16) __bf16 As[8][64][8];
  __shared__ __align__(16) __bf16 Bs[8][64][8];
  const int tid = threadIdx.x, lane = tid & 63, wave = tid >> 6;
  const int m0 = blockIdx.y << 6;
  const int wm = (wave >> 1) << 5, wn = (wave & 1) << 5;
  const int lr = lane & 15, kh = lane >> 4;
  const int ar0 = tid >> 3, akb = tid & 7;
  const int bn = tid & 63, bkb0 = tid >> 6;
  f32x4 acc00 = {0,0,0,0}, acc01 = {0,0,0,0}, acc10 = {0,0,0,0}, acc11 = {0,0,0,0};
  const int kmax = m0 + 64;   // P == 0 beyond diagonal
  for (int k0 = 0; k0 < kmax; k0 += 64) {
#pragma unroll
    for (int r = 0; r < 2; ++r) {
      const int row = ar0 + r * 32;
      const float* ap = sp + (size_t)(m0 + row) * TSEQ + k0 + akb * 8;
      float4 v0 = *(const float4*)ap, v1 = *(const float4*)(ap + 4);
      bf16x8 w = {(__bf16)v0.x, (__bf16)v0.y, (__bf16)v0.z, (__bf16)v0.w,
                  (__bf16)v1.x, (__bf16)v1.y, (__bf16)v1.z, (__bf16)v1.w};
      *(bf16x8*)&As[akb][row ^ akb][0] = w;
    }
#pragma unroll
    for (int r = 0; r < 2; ++r) {
      const int kb2 = bkb0 + r * 4;
      float f[8];
#pragma unroll
      for (int i = 0; i < 8; ++i)
        f[i] = vp[(size_t)(k0 + kb2 * 8 + i) * HDIM + bn];
      bf16x8 w = {(__bf16)f[0], (__bf16)f[1], (__bf16)f[2], (__bf16)f[3],
                  (__bf16)f[4], (__bf16)f[5], (__bf16)f[6], (__bf16)f[7]};
      *(bf16x8*)&Bs[kb2][bn ^ kb2][0] = w;
    }
    __syncthreads();
#pragma unroll
    for (int ks = 0; ks < 2; ++ks) {
      const int kidx = ks * 4 + kh;
      bf16x8 a0 = *(const bf16x8*)&As[kidx][(wm + lr) ^ kidx][0];
      bf16x8 a1 = *(const bf16x8*)&As[kidx][(wm + 16 + lr) ^ kidx][0];
      bf16x8 b0 = *(const bf16x8*)&Bs[kidx][(wn + lr) ^ kidx][0];
      bf16x8 b1 = *(const bf16x8*)&Bs[kidx][(wn + 16 + lr) ^ kidx][0];
      acc00 = MFMA(a0, b0, acc00);
      acc01 = MFMA(a0, b1, acc01);
      acc10 = MFMA(a1, b0, acc10);
      acc11 = MFMA(a1, b1, acc11);
    }
    __syncthreads();
  }
#pragma unroll
  for (int mi = 0; mi < 2; ++mi)
#pragma unroll
    for (int ni = 0; ni < 2; ++ni) {
      f32x4 c = (mi == 0) ? (ni == 0 ? acc00 : acc01) : (ni == 0 ? acc10 : acc11);
      const int col = wn + ni * 16 + lr;     // 0..63 = s
#pragma unroll
      for (int j = 0; j < 4; ++j) {
        const int row = m0 + wm + mi * 16 + (kh << 2) + j;  // = t (+b offset)
        y2[((size_t)(b * TSEQ) + row) * EDIM + h * HDIM + col] = c[j];
      }
    }
}

// ---------------------------------------------------------------- launcher
extern "C" void kernel_launch(void* const* d_in, const int* in_sizes, int n_in,
                              void* d_out, int out_size, void* d_ws, size_t ws_size,
                              hipStream_t stream) {
  const int*   tokens  = (const int*)d_in[0];
  const float* emb     = (const float*)d_in[1];
  const float* Wqkv    = (const float*)d_in[2];
  const float* bqkv    = (const float*)d_in[3];
  const float* Wo      = (const float*)d_in[4];
  const float* bo      = (const float*)d_in[5];
  const float* W1      = (const float*)d_in[6];
  const float* b1      = (const float*)d_in[7];
  const float* W3      = (const float*)d_in[8];
  const float* b3      = (const float*)d_in[9];
  const float* W2      = (const float*)d_in[10];
  const float* b2      = (const float*)d_in[11];
  const float* g_mha   = (const float*)d_in[12];
  const float* g_ff    = (const float*)d_in[13];
  const float* g_final = (const float*)d_in[14];
  const float* Wout    = (const float*)d_in[15];
  const float* bout    = (const float*)d_in[16];
  float* out = (float*)d_out;

  float* ws = (float*)d_ws;
  const size_t M1 = 1u << 20;
  float* x    = ws;
  float* y    = ws + 1 * M1;
  float* qb   = ws + 2 * M1;
  float* kb   = ws + 3 * M1;
  float* vb   = ws + 4 * M1;
  float* y2   = ws + 5 * M1;
  float* big  = ws + 6 * M1;                // scores (8.39M f) / SwiGLU u (2.82M f)
  float* part = big + (size_t)32 * TSEQ * TSEQ;
  float* scal = part + 256;

  k_embed<<<MTOK, 256, 0, stream>>>(tokens, emb, x);

  for (int l = 0; l < NLAYER; ++l) {
    // --- MHA ---
    k_red1<<<256, 256, 0, stream>>>(x, part);
    k_red2<<<1, 256, 0, stream>>>(part, scal);
    k_rms<<<1024, 256, 0, stream>>>(x, g_mha + (size_t)l * EDIM, scal, y);
    mm_qkv<<<dim3(48, 16), 256, 0, stream>>>(
        y, Wqkv + (size_t)l * EDIM * 3 * EDIM, bqkv + (size_t)l * 3 * EDIM, qb, kb, vb);
    mm_qk<<<dim3(8, 8, 32), 256, 0, stream>>>(qb, kb, big);
    k_softmax<<<4096, 256, 0, stream>>>(big);
    mm_pv<<<dim3(1, 8, 32), 256, 0, stream>>>(big, vb, y2);
    mm_g<1><<<dim3(16, 16), 256, 0, stream>>>(
        y2, Wo + (size_t)l * EDIM * EDIM, bo + (size_t)l * EDIM, x, x,
        EDIM, EDIM, EDIM);
    // --- SwiGLU FFN ---
    k_red1<<<256, 256, 0, stream>>>(x, part);
    k_red2<<<1, 256, 0, stream>>>(part, scal);
    k_rms<<<1024, 256, 0, stream>>>(x, g_ff + (size_t)l * EDIM, scal, y);
    mm_w13<<<dim3(43, 16), 256, 0, stream>>>(
        y, W1 + (size_t)l * EDIM * DFFDIM, W3 + (size_t)l * EDIM * DFFDIM,
        b1 + (size_t)l * DFFDIM, b3 + (size_t)l * DFFDIM, big);
    mm_g<1><<<dim3(16, 16), 256, 0, stream>>>(
        big, W2 + (size_t)l * DFFDIM * EDIM, b2 + (size_t)l * EDIM, x, x,
        EDIM, DPAD, DFFDIM);
  }

  // --- final RMS + vocab head ---
  k_red1<<<256, 256, 0, stream>>>(x, part);
  k_red2<<<1, 256, 0, stream>>>(part, scal);
  k_rms<<<1024, 256, 0, stream>>>(x, g_final, scal, y);
  mm_g<0><<<dim3(127, 16), 256, 0, stream>>>(
      y, Wout, bout, nullptr, out, VOCAB, EDIM, EDIM);
}

// Round 3
// 11040.906 us; speedup vs baseline: 1.5580x; 1.5580x over previous
//
#include <hip/hip_runtime.h>
#include <hip/hip_bf16.h>
#include <math.h>

#define EDIM   1024
#define TSEQ   512
#define NBATCH 2
#define NHEAD  16
#define HDIM   64
#define NLAYER 24
#define VOCAB  8124
#define DFFDIM 2730
#define DPAD   2752              // 43*64, padded SwiGLU width
#define MTOK   (NBATCH*TSEQ)     // 1024 rows
#define NELEM  (MTOK*EDIM)       // 1048576
#define EPSF   1e-5f
#define SCALEF (1.0f/32.0f)      // 1/sqrt(emb_dim)
#define NEGBIG (-1e30f)

typedef __bf16 bf16x8 __attribute__((ext_vector_type(8)));
typedef float  f32x4  __attribute__((ext_vector_type(4)));

#define MFMA(a, b, c) __builtin_amdgcn_mfma_f32_16x16x32_bf16((a), (b), (c), 0, 0, 0)

__device__ __forceinline__ bf16x8 cvt8(float4 a, float4 b) {
  bf16x8 w = {(__bf16)a.x, (__bf16)a.y, (__bf16)a.z, (__bf16)a.w,
              (__bf16)b.x, (__bf16)b.y, (__bf16)b.z, (__bf16)b.w};
  return w;
}

// ---------------------------------------------------------------- embedding+PE
__global__ __launch_bounds__(256) void k_embed(const int* __restrict__ tok,
                                               const float* __restrict__ emb,
                                               float* __restrict__ x) {
  const int bt = blockIdx.x;
  const int t  = bt & (TSEQ - 1);
  const int tk = tok[bt];
  const float* er = emb + (size_t)tk * EDIM;
  float* xr = x + (size_t)bt * EDIM;
  for (int e = threadIdx.x * 4; e < EDIM; e += 256 * 4) {
    float4 v = *(const float4*)(er + e);
    float vv[4] = {v.x, v.y, v.z, v.w};
    float ou[4];
#pragma unroll
    for (int j = 0; j < 4; ++j) {
      int ee = e + j;
      int i2 = ee & ~1;
      float freq = expf(-(float)i2 * (9.210340371976184f / 1024.0f));
      float ang  = (float)t * freq;
      ou[j] = vv[j] + ((ee & 1) ? cosf(ang) : sinf(ang));
    }
    *(float4*)(xr + e) = make_float4(ou[0], ou[1], ou[2], ou[3]);
  }
}

// ---------------------------------------------------------------- global RMS reduce
__global__ __launch_bounds__(256) void k_red1(const float* __restrict__ xin,
                                              float* __restrict__ part) {
  float s = 0.f;
  for (int i = (blockIdx.x * 256 + threadIdx.x) * 4; i < NELEM; i += 256 * 256 * 4) {
    float4 v = *(const float4*)(xin + i);
    s += v.x * v.x + v.y * v.y + v.z * v.z + v.w * v.w;
  }
#pragma unroll
  for (int o = 32; o > 0; o >>= 1) s += __shfl_down(s, o);
  __shared__ float sm[4];
  if ((threadIdx.x & 63) == 0) sm[threadIdx.x >> 6] = s;
  __syncthreads();
  if (threadIdx.x == 0) part[blockIdx.x] = sm[0] + sm[1] + sm[2] + sm[3];
}

__global__ __launch_bounds__(256) void k_red2(const float* __restrict__ part,
                                              float* __restrict__ scale) {
  float s = part[threadIdx.x];
#pragma unroll
  for (int o = 32; o > 0; o >>= 1) s += __shfl_down(s, o);
  __shared__ float sm[4];
  if ((threadIdx.x & 63) == 0) sm[threadIdx.x >> 6] = s;
  __syncthreads();
  if (threadIdx.x == 0) {
    float tot = sm[0] + sm[1] + sm[2] + sm[3];
    scale[0] = 1.0f / sqrtf(tot / (float)NELEM + EPSF);
  }
}

// ================================================================ MFMA GEMMs
// 64x64 tile, BK=64, 4 waves (32x32 wave tile, 2x2 frags of 16x16x32 bf16).
// Double-buffered LDS with register prefetch: one barrier per K-step.
// A frag: row=lane&15, k=(lane>>4)*8+i.  B frag: col=lane&15, same k.
// C/D: col=lane&15, row=(lane>>4)*4+j.
// FUSE: A := A * scal[0] * g[k]  (RMS fused into staging).

template <int RES, int FUSE>
__global__ __launch_bounds__(256) void mm_g(const float* __restrict__ A,
                                            const float* __restrict__ W,
                                            const float* __restrict__ bias,
                                            const float* __restrict__ res,
                                            const float* __restrict__ g,
                                            const float* __restrict__ scal,
                                            float* __restrict__ out,
                                            int N, int K, int Kreal) {
  __shared__ __align__(16) __bf16 As[2][8][64][8];
  __shared__ __align__(16) __bf16 Bs[2][8][64][8];
  const int tid = threadIdx.x, lane = tid & 63, wave = tid >> 6;
  const int m0 = blockIdx.y << 6, n0 = blockIdx.x << 6;
  const int wm = (wave >> 1) << 5, wn = (wave & 1) << 5;
  const int lr = lane & 15, kh = lane >> 4;
  const int ar0 = tid >> 3, akb = tid & 7;
  const int bn = tid & 63, bkb0 = tid >> 6;
  const bool bok = (n0 + bn) < N;
  const float sc = FUSE ? scal[0] : 1.0f;

  float4 ra[2][2]; float4 rg[2]; float rb[2][8];
  f32x4 acc00 = {0,0,0,0}, acc01 = {0,0,0,0}, acc10 = {0,0,0,0}, acc11 = {0,0,0,0};

  auto LOADT = [&](int k0) {
#pragma unroll
    for (int r = 0; r < 2; ++r) {
      const float* ap = A + (size_t)(m0 + ar0 + r * 32) * K + k0 + akb * 8;
      ra[r][0] = *(const float4*)ap; ra[r][1] = *(const float4*)(ap + 4);
    }
    if (FUSE) {
      const float* gp = g + k0 + akb * 8;
      rg[0] = *(const float4*)gp; rg[1] = *(const float4*)(gp + 4);
    }
#pragma unroll
    for (int r = 0; r < 2; ++r) {
      const int kb2 = bkb0 + r * 4;
#pragma unroll
      for (int i = 0; i < 8; ++i) {
        const int k = k0 + kb2 * 8 + i;
        rb[r][i] = (bok && k < Kreal) ? W[(size_t)k * N + n0 + bn] : 0.f;
      }
    }
  };
  auto STORET = [&](int buf) {
#pragma unroll
    for (int r = 0; r < 2; ++r) {
      float4 va = ra[r][0], vb2 = ra[r][1];
      if (FUSE) {
        va.x *= sc * rg[0].x; va.y *= sc * rg[0].y; va.z *= sc * rg[0].z; va.w *= sc * rg[0].w;
        vb2.x *= sc * rg[1].x; vb2.y *= sc * rg[1].y; vb2.z *= sc * rg[1].z; vb2.w *= sc * rg[1].w;
      }
      *(bf16x8*)&As[buf][akb][(ar0 + r * 32) ^ akb][0] = cvt8(va, vb2);
    }
#pragma unroll
    for (int r = 0; r < 2; ++r) {
      const int kb2 = bkb0 + r * 4;
      bf16x8 w = {(__bf16)rb[r][0], (__bf16)rb[r][1], (__bf16)rb[r][2], (__bf16)rb[r][3],
                  (__bf16)rb[r][4], (__bf16)rb[r][5], (__bf16)rb[r][6], (__bf16)rb[r][7]};
      *(bf16x8*)&Bs[buf][kb2][bn ^ kb2][0] = w;
    }
  };
  auto COMPUTET = [&](int buf) {
#pragma unroll
    for (int ks = 0; ks < 2; ++ks) {
      const int kidx = ks * 4 + kh;
      bf16x8 a0 = *(const bf16x8*)&As[buf][kidx][(wm + lr) ^ kidx][0];
      bf16x8 a1 = *(const bf16x8*)&As[buf][kidx][(wm + 16 + lr) ^ kidx][0];
      bf16x8 b0 = *(const bf16x8*)&Bs[buf][kidx][(wn + lr) ^ kidx][0];
      bf16x8 b1 = *(const bf16x8*)&Bs[buf][kidx][(wn + 16 + lr) ^ kidx][0];
      acc00 = MFMA(a0, b0, acc00); acc01 = MFMA(a0, b1, acc01);
      acc10 = MFMA(a1, b0, acc10); acc11 = MFMA(a1, b1, acc11);
    }
  };

  LOADT(0); STORET(0); __syncthreads();
  int cur = 0;
  const int nsteps = K >> 6;
  for (int s = 1; s < nsteps; ++s) {
    LOADT(s << 6);
    COMPUTET(cur);
    STORET(cur ^ 1);
    __syncthreads();
    cur ^= 1;
  }
  COMPUTET(cur);

#pragma unroll
  for (int mi = 0; mi < 2; ++mi)
#pragma unroll
    for (int ni = 0; ni < 2; ++ni) {
      f32x4 c = (mi == 0) ? (ni == 0 ? acc00 : acc01) : (ni == 0 ? acc10 : acc11);
      const int col = n0 + wn + ni * 16 + lr;
      if (col < N) {
        const float bs = bias[col];
#pragma unroll
        for (int j = 0; j < 4; ++j) {
          const int row = m0 + wm + mi * 16 + (kh << 2) + j;
          float v = c[j] + bs;
          if (RES) v += res[(size_t)row * N + col];
          out[(size_t)row * N + col] = v;
        }
      }
    }
}

// ---- QKV GEMM (N=3072, K=1024), RMS fused, q/k/v scatter epilogue
__global__ __launch_bounds__(256) void mm_qkv(const float* __restrict__ A,
                                              const float* __restrict__ W,
                                              const float* __restrict__ bias,
                                              const float* __restrict__ g,
                                              const float* __restrict__ scal,
                                              float* __restrict__ qb,
                                              float* __restrict__ kb,
                                              float* __restrict__ vb) {
  const int N = 3 * EDIM, K = EDIM;
  __shared__ __align__(16) __bf16 As[2][8][64][8];
  __shared__ __align__(16) __bf16 Bs[2][8][64][8];
  const int tid = threadIdx.x, lane = tid & 63, wave = tid >> 6;
  const int m0 = blockIdx.y << 6, n0 = blockIdx.x << 6;
  const int wm = (wave >> 1) << 5, wn = (wave & 1) << 5;
  const int lr = lane & 15, kh = lane >> 4;
  const int ar0 = tid >> 3, akb = tid & 7;
  const int bn = tid & 63, bkb0 = tid >> 6;
  const float sc = scal[0];

  float4 ra[2][2]; float4 rg[2]; float rb[2][8];
  f32x4 acc00 = {0,0,0,0}, acc01 = {0,0,0,0}, acc10 = {0,0,0,0}, acc11 = {0,0,0,0};

  auto LOADT = [&](int k0) {
#pragma unroll
    for (int r = 0; r < 2; ++r) {
      const float* ap = A + (size_t)(m0 + ar0 + r * 32) * K + k0 + akb * 8;
      ra[r][0] = *(const float4*)ap; ra[r][1] = *(const float4*)(ap + 4);
    }
    const float* gp = g + k0 + akb * 8;
    rg[0] = *(const float4*)gp; rg[1] = *(const float4*)(gp + 4);
#pragma unroll
    for (int r = 0; r < 2; ++r) {
      const int kb2 = bkb0 + r * 4;
#pragma unroll
      for (int i = 0; i < 8; ++i)
        rb[r][i] = W[(size_t)(k0 + kb2 * 8 + i) * N + n0 + bn];
    }
  };
  auto STORET = [&](int buf) {
#pragma unroll
    for (int r = 0; r < 2; ++r) {
      float4 va = ra[r][0], vb2 = ra[r][1];
      va.x *= sc * rg[0].x; va.y *= sc * rg[0].y; va.z *= sc * rg[0].z; va.w *= sc * rg[0].w;
      vb2.x *= sc * rg[1].x; vb2.y *= sc * rg[1].y; vb2.z *= sc * rg[1].z; vb2.w *= sc * rg[1].w;
      *(bf16x8*)&As[buf][akb][(ar0 + r * 32) ^ akb][0] = cvt8(va, vb2);
    }
#pragma unroll
    for (int r = 0; r < 2; ++r) {
      const int kb2 = bkb0 + r * 4;
      bf16x8 w = {(__bf16)rb[r][0], (__bf16)rb[r][1], (__bf16)rb[r][2], (__bf16)rb[r][3],
                  (__bf16)rb[r][4], (__bf16)rb[r][5], (__bf16)rb[r][6], (__bf16)rb[r][7]};
      *(bf16x8*)&Bs[buf][kb2][bn ^ kb2][0] = w;
    }
  };
  auto COMPUTET = [&](int buf) {
#pragma unroll
    for (int ks = 0; ks < 2; ++ks) {
      const int kidx = ks * 4 + kh;
      bf16x8 a0 = *(const bf16x8*)&As[buf][kidx][(wm + lr) ^ kidx][0];
      bf16x8 a1 = *(const bf16x8*)&As[buf][kidx][(wm + 16 + lr) ^ kidx][0];
      bf16x8 b0 = *(const bf16x8*)&Bs[buf][kidx][(wn + lr) ^ kidx][0];
      bf16x8 b1 = *(const bf16x8*)&Bs[buf][kidx][(wn + 16 + lr) ^ kidx][0];
      acc00 = MFMA(a0, b0, acc00); acc01 = MFMA(a0, b1, acc01);
      acc10 = MFMA(a1, b0, acc10); acc11 = MFMA(a1, b1, acc11);
    }
  };

  LOADT(0); STORET(0); __syncthreads();
  int cur = 0;
  for (int s = 1; s < (K >> 6); ++s) {
    LOADT(s << 6);
    COMPUTET(cur);
    STORET(cur ^ 1);
    __syncthreads();
    cur ^= 1;
  }
  COMPUTET(cur);

#pragma unroll
  for (int mi = 0; mi < 2; ++mi)
#pragma unroll
    for (int ni = 0; ni < 2; ++ni) {
      f32x4 c = (mi == 0) ? (ni == 0 ? acc00 : acc01) : (ni == 0 ? acc10 : acc11);
      const int col = n0 + wn + ni * 16 + lr;
      const float bs = bias[col];
      const int h = col / (3 * HDIM);
      const int rsel = (col >> 6) % 3;
      const int s2 = col & (HDIM - 1);
      float* dst = (rsel == 0) ? qb : (rsel == 1) ? kb : vb;
#pragma unroll
      for (int j = 0; j < 4; ++j) {
        const int row = m0 + wm + mi * 16 + (kh << 2) + j;
        const int b = row >> 9, t = row & (TSEQ - 1);
        dst[((size_t)(b * NHEAD + h) * TSEQ + t) * HDIM + s2] = c[j] + bs;
      }
    }
}

// ---- fused W1/W3 SwiGLU GEMM, RMS fused, prefetch
__global__ __launch_bounds__(256) void mm_w13(const float* __restrict__ A,
                                              const float* __restrict__ W1,
                                              const float* __restrict__ W3,
                                              const float* __restrict__ b1,
                                              const float* __restrict__ b3,
                                              const float* __restrict__ g,
                                              const float* __restrict__ scal,
                                              float* __restrict__ u) {
  const int N = DFFDIM, K = EDIM;
  __shared__ __align__(16) __bf16 As[2][8][64][8];
  __shared__ __align__(16) __bf16 B1s[2][8][64][8];
  __shared__ __align__(16) __bf16 B3s[2][8][64][8];
  const int tid = threadIdx.x, lane = tid & 63, wave = tid >> 6;
  const int m0 = blockIdx.y << 6, n0 = blockIdx.x << 6;
  const int wm = (wave >> 1) << 5, wn = (wave & 1) << 5;
  const int lr = lane & 15, kh = lane >> 4;
  const int ar0 = tid >> 3, akb = tid & 7;
  const int bn = tid & 63, bkb0 = tid >> 6;
  const bool bok = (n0 + bn) < N;
  const float sc = scal[0];

  float4 ra[2][2]; float4 rg[2]; float rb1[2][8], rb3[2][8];
  f32x4 p00 = {0,0,0,0}, p01 = {0,0,0,0}, p10 = {0,0,0,0}, p11 = {0,0,0,0};
  f32x4 q00 = {0,0,0,0}, q01 = {0,0,0,0}, q10 = {0,0,0,0}, q11 = {0,0,0,0};

  auto LOADT = [&](int k0) {
#pragma unroll
    for (int r = 0; r < 2; ++r) {
      const float* ap = A + (size_t)(m0 + ar0 + r * 32) * K + k0 + akb * 8;
      ra[r][0] = *(const float4*)ap; ra[r][1] = *(const float4*)(ap + 4);
    }
    const float* gp = g + k0 + akb * 8;
    rg[0] = *(const float4*)gp; rg[1] = *(const float4*)(gp + 4);
#pragma unroll
    for (int r = 0; r < 2; ++r) {
      const int kb2 = bkb0 + r * 4;
#pragma unroll
      for (int i = 0; i < 8; ++i) {
        const size_t off = (size_t)(k0 + kb2 * 8 + i) * N + n0 + bn;
        rb1[r][i] = bok ? W1[off] : 0.f;
        rb3[r][i] = bok ? W3[off] : 0.f;
      }
    }
  };
  auto STORET = [&](int buf) {
#pragma unroll
    for (int r = 0; r < 2; ++r) {
      float4 va = ra[r][0], vb2 = ra[r][1];
      va.x *= sc * rg[0].x; va.y *= sc * rg[0].y; va.z *= sc * rg[0].z; va.w *= sc * rg[0].w;
      vb2.x *= sc * rg[1].x; vb2.y *= sc * rg[1].y; vb2.z *= sc * rg[1].z; vb2.w *= sc * rg[1].w;
      *(bf16x8*)&As[buf][akb][(ar0 + r * 32) ^ akb][0] = cvt8(va, vb2);
    }
#pragma unroll
    for (int r = 0; r < 2; ++r) {
      const int kb2 = bkb0 + r * 4;
      bf16x8 w1 = {(__bf16)rb1[r][0], (__bf16)rb1[r][1], (__bf16)rb1[r][2], (__bf16)rb1[r][3],
                   (__bf16)rb1[r][4], (__bf16)rb1[r][5], (__bf16)rb1[r][6], (__bf16)rb1[r][7]};
      bf16x8 w3 = {(__bf16)rb3[r][0], (__bf16)rb3[r][1], (__bf16)rb3[r][2], (__bf16)rb3[r][3],
                   (__bf16)rb3[r][4], (__bf16)rb3[r][5], (__bf16)rb3[r][6], (__bf16)rb3[r][7]};
      *(bf16x8*)&B1s[buf][kb2][bn ^ kb2][0] = w1;
      *(bf16x8*)&B3s[buf][kb2][bn ^ kb2][0] = w3;
    }
  };
  auto COMPUTET = [&](int buf) {
#pragma unroll
    for (int ks = 0; ks < 2; ++ks) {
      const int kidx = ks * 4 + kh;
      bf16x8 a0 = *(const bf16x8*)&As[buf][kidx][(wm + lr) ^ kidx][0];
      bf16x8 a1 = *(const bf16x8*)&As[buf][kidx][(wm + 16 + lr) ^ kidx][0];
      bf16x8 c0 = *(const bf16x8*)&B1s[buf][kidx][(wn + lr) ^ kidx][0];
      bf16x8 c1 = *(const bf16x8*)&B1s[buf][kidx][(wn + 16 + lr) ^ kidx][0];
      bf16x8 d0 = *(const bf16x8*)&B3s[buf][kidx][(wn + lr) ^ kidx][0];
      bf16x8 d1 = *(const bf16x8*)&B3s[buf][kidx][(wn + 16 + lr) ^ kidx][0];
      p00 = MFMA(a0, c0, p00); p01 = MFMA(a0, c1, p01);
      p10 = MFMA(a1, c0, p10); p11 = MFMA(a1, c1, p11);
      q00 = MFMA(a0, d0, q00); q01 = MFMA(a0, d1, q01);
      q10 = MFMA(a1, d0, q10); q11 = MFMA(a1, d1, q11);
    }
  };

  LOADT(0); STORET(0); __syncthreads();
  int cur = 0;
  for (int s = 1; s < (K >> 6); ++s) {
    LOADT(s << 6);
    COMPUTET(cur);
    STORET(cur ^ 1);
    __syncthreads();
    cur ^= 1;
  }
  COMPUTET(cur);

#pragma unroll
  for (int mi = 0; mi < 2; ++mi)
#pragma unroll
    for (int ni = 0; ni < 2; ++ni) {
      f32x4 c1 = (mi == 0) ? (ni == 0 ? p00 : p01) : (ni == 0 ? p10 : p11);
      f32x4 c3 = (mi == 0) ? (ni == 0 ? q00 : q01) : (ni == 0 ? q10 : q11);
      const int col = n0 + wn + ni * 16 + lr;
      const bool ok = col < N;
      const float bb1 = ok ? b1[col] : 0.f;
      const float bb3 = ok ? b3[col] : 0.f;
#pragma unroll
      for (int j = 0; j < 4; ++j) {
        const int row = m0 + wm + mi * 16 + (kh << 2) + j;
        float v = 0.f;
        if (ok) {
          const float a1v = c1[j] + bb1;
          const float a3v = c3[j] + bb3;
          v = a1v * (1.0f / (1.0f + __expf(-a1v))) * a3v;
        }
        u[(size_t)row * DPAD + col] = v;
      }
    }
}

// ---- fused flash attention: per (q-tile, b*h), online softmax
__global__ __launch_bounds__(256) void k_flash(const float* __restrict__ qb,
                                               const float* __restrict__ kbuf,
                                               const float* __restrict__ vbuf,
                                               float* __restrict__ y2) {
  const int qt = blockIdx.x, bh = blockIdx.y;
  const int b = bh >> 4, h = bh & 15;
  const int m0 = qt << 6;
  const float* qp = qb   + (size_t)bh * TSEQ * HDIM;
  const float* kp = kbuf + (size_t)bh * TSEQ * HDIM;
  const float* vp = vbuf + (size_t)bh * TSEQ * HDIM;
  __shared__ __align__(16) __bf16 Qs[8][64][8], Ks[8][64][8], Vs[8][64][8], Ps[8][64][8];
  __shared__ float wmax[2][64], wsum[2][64];
  const int tid = threadIdx.x, lane = tid & 63, wave = tid >> 6;
  const int wm = (wave >> 1) << 5, wn = (wave & 1) << 5;
  const int lr = lane & 15, kh = lane >> 4;
  const int ar0 = tid >> 3, akb = tid & 7;
  const int vs = tid & 63, vkb0 = tid >> 6;

  // stage Q once
#pragma unroll
  for (int r = 0; r < 2; ++r) {
    const int row = ar0 + r * 32;
    const float* ap = qp + (size_t)(m0 + row) * HDIM + akb * 8;
    float4 v0 = *(const float4*)ap, v1 = *(const float4*)(ap + 4);
    *(bf16x8*)&Qs[akb][row ^ akb][0] = cvt8(v0, v1);
  }
  float m_[2][4], l_[2][4];
#pragma unroll
  for (int mi = 0; mi < 2; ++mi)
#pragma unroll
    for (int j = 0; j < 4; ++j) { m_[mi][j] = NEGBIG; l_[mi][j] = 0.f; }
  f32x4 o00 = {0,0,0,0}, o01 = {0,0,0,0}, o10 = {0,0,0,0}, o11 = {0,0,0,0};

  for (int kt = 0; kt <= qt; ++kt) {
    const int n0 = kt << 6;
    __syncthreads();  // B0: previous Ks/Vs/Ps reads done (also Qs visibility, first iter)
#pragma unroll
    for (int r = 0; r < 2; ++r) {
      const int row = ar0 + r * 32;
      const float* ap = kp + (size_t)(n0 + row) * HDIM + akb * 8;
      float4 v0 = *(const float4*)ap, v1 = *(const float4*)(ap + 4);
      *(bf16x8*)&Ks[akb][row ^ akb][0] = cvt8(v0, v1);
    }
#pragma unroll
    for (int r = 0; r < 2; ++r) {
      const int kb2 = vkb0 + r * 4;
      float f[8];
#pragma unroll
      for (int i = 0; i < 8; ++i) f[i] = vp[(size_t)(n0 + kb2 * 8 + i) * HDIM + vs];
      bf16x8 w = {(__bf16)f[0], (__bf16)f[1], (__bf16)f[2], (__bf16)f[3],
                  (__bf16)f[4], (__bf16)f[5], (__bf16)f[6], (__bf16)f[7]};
      *(bf16x8*)&Vs[kb2][vs ^ kb2][0] = w;
    }
    __syncthreads();  // B1: K/V tiles ready

    f32x4 s00 = {0,0,0,0}, s01 = {0,0,0,0}, s10 = {0,0,0,0}, s11 = {0,0,0,0};
#pragma unroll
    for (int ks = 0; ks < 2; ++ks) {
      const int kidx = ks * 4 + kh;
      bf16x8 a0 = *(const bf16x8*)&Qs[kidx][(wm + lr) ^ kidx][0];
      bf16x8 a1 = *(const bf16x8*)&Qs[kidx][(wm + 16 + lr) ^ kidx][0];
      bf16x8 b0 = *(const bf16x8*)&Ks[kidx][(wn + lr) ^ kidx][0];
      bf16x8 b1 = *(const bf16x8*)&Ks[kidx][(wn + 16 + lr) ^ kidx][0];
      s00 = MFMA(a0, b0, s00); s01 = MFMA(a0, b1, s01);
      s10 = MFMA(a1, b0, s10); s11 = MFMA(a1, b1, s11);
    }
    // scale + mask + per-lane row max
    float pv_[2][2][4], rmx[2][4];
#pragma unroll
    for (int mi = 0; mi < 2; ++mi)
#pragma unroll
      for (int j = 0; j < 4; ++j) {
        const int grow = m0 + wm + mi * 16 + (kh << 2) + j;
        float best = NEGBIG;
#pragma unroll
        for (int ni = 0; ni < 2; ++ni) {
          f32x4 sfr = (mi == 0) ? (ni == 0 ? s00 : s01) : (ni == 0 ? s10 : s11);
          const int gcol = n0 + wn + ni * 16 + lr;
          float t = sfr[j] * SCALEF;
          if (gcol > grow) t = NEGBIG;
          pv_[mi][ni][j] = t;
          best = fmaxf(best, t);
        }
        float v = best;
        v = fmaxf(v, __shfl_xor(v, 1)); v = fmaxf(v, __shfl_xor(v, 2));
        v = fmaxf(v, __shfl_xor(v, 4)); v = fmaxf(v, __shfl_xor(v, 8));
        rmx[mi][j] = v;
        wmax[wave & 1][wm + mi * 16 + (kh << 2) + j] = v;
      }
    __syncthreads();  // B2: wmax visible

    float alpha[2][4];
#pragma unroll
    for (int mi = 0; mi < 2; ++mi)
#pragma unroll
      for (int j = 0; j < 4; ++j) {
        const int rl = wm + mi * 16 + (kh << 2) + j;
        const float tmax = fmaxf(wmax[0][rl], wmax[1][rl]);
        const float mn = fmaxf(m_[mi][j], tmax);
        alpha[mi][j] = __expf(m_[mi][j] - mn);
        m_[mi][j] = mn;
        float rs = 0.f;
#pragma unroll
        for (int ni = 0; ni < 2; ++ni) {
          const float p = __expf(pv_[mi][ni][j] - mn);
          pv_[mi][ni][j] = p;
          rs += p;
        }
        rs += __shfl_xor(rs, 1); rs += __shfl_xor(rs, 2);
        rs += __shfl_xor(rs, 4); rs += __shfl_xor(rs, 8);
        wsum[wave & 1][rl] = rs;
      }
    // P -> LDS (bf16), A-operand layout
#pragma unroll
    for (int mi = 0; mi < 2; ++mi)
#pragma unroll
      for (int ni = 0; ni < 2; ++ni)
#pragma unroll
        for (int j = 0; j < 4; ++j) {
          const int prow = wm + mi * 16 + (kh << 2) + j;
          const int pcol = wn + ni * 16 + lr;
          Ps[pcol >> 3][prow ^ (pcol >> 3)][pcol & 7] = (__bf16)pv_[mi][ni][j];
        }
    __syncthreads();  // B3: wsum & Ps visible

#pragma unroll
    for (int mi = 0; mi < 2; ++mi)
#pragma unroll
      for (int j = 0; j < 4; ++j) {
        const int rl = wm + mi * 16 + (kh << 2) + j;
        l_[mi][j] = l_[mi][j] * alpha[mi][j] + wsum[0][rl] + wsum[1][rl];
      }
#pragma unroll
    for (int j = 0; j < 4; ++j) {
      o00[j] *= alpha[0][j]; o01[j] *= alpha[0][j];
      o10[j] *= alpha[1][j]; o11[j] *= alpha[1][j];
    }
#pragma unroll
    for (int ks = 0; ks < 2; ++ks) {
      const int kidx = ks * 4 + kh;
      bf16x8 a0 = *(const bf16x8*)&Ps[kidx][(wm + lr) ^ kidx][0];
      bf16x8 a1 = *(const bf16x8*)&Ps[kidx][(wm + 16 + lr) ^ kidx][0];
      bf16x8 b0 = *(const bf16x8*)&Vs[kidx][(wn + lr) ^ kidx][0];
      bf16x8 b1 = *(const bf16x8*)&Vs[kidx][(wn + 16 + lr) ^ kidx][0];
      o00 = MFMA(a0, b0, o00); o01 = MFMA(a0, b1, o01);
      o10 = MFMA(a1, b0, o10); o11 = MFMA(a1, b1, o11);
    }
  }

#pragma unroll
  for (int mi = 0; mi < 2; ++mi)
#pragma unroll
    for (int ni = 0; ni < 2; ++ni) {
      f32x4 oo = (mi == 0) ? (ni == 0 ? o00 : o01) : (ni == 0 ? o10 : o11);
      const int col = wn + ni * 16 + lr;
#pragma unroll
      for (int j = 0; j < 4; ++j) {
        const int row = m0 + wm + mi * 16 + (kh << 2) + j;
        y2[((size_t)(b * TSEQ) + row) * EDIM + h * HDIM + col] = oo[j] / l_[mi][j];
      }
    }
}

// ---------------------------------------------------------------- launcher
extern "C" void kernel_launch(void* const* d_in, const int* in_sizes, int n_in,
                              void* d_out, int out_size, void* d_ws, size_t ws_size,
                              hipStream_t stream) {
  const int*   tokens  = (const int*)d_in[0];
  const float* emb     = (const float*)d_in[1];
  const float* Wqkv    = (const float*)d_in[2];
  const float* bqkv    = (const float*)d_in[3];
  const float* Wo      = (const float*)d_in[4];
  const float* bo      = (const float*)d_in[5];
  const float* W1      = (const float*)d_in[6];
  const float* b1      = (const float*)d_in[7];
  const float* W3      = (const float*)d_in[8];
  const float* b3      = (const float*)d_in[9];
  const float* W2      = (const float*)d_in[10];
  const float* b2      = (const float*)d_in[11];
  const float* g_mha   = (const float*)d_in[12];
  const float* g_ff    = (const float*)d_in[13];
  const float* g_final = (const float*)d_in[14];
  const float* Wout    = (const float*)d_in[15];
  const float* bout    = (const float*)d_in[16];
  float* out = (float*)d_out;

  float* ws = (float*)d_ws;
  const size_t M1 = 1u << 20;
  float* x    = ws;
  float* qb   = ws + 1 * M1;
  float* kb   = ws + 2 * M1;
  float* vb   = ws + 3 * M1;
  float* y2   = ws + 4 * M1;
  float* big  = ws + 5 * M1;                    // SwiGLU u, 1024 x 2752
  float* part = big + (size_t)MTOK * DPAD;
  float* scal = part + 256;

  k_embed<<<MTOK, 256, 0, stream>>>(tokens, emb, x);

  for (int l = 0; l < NLAYER; ++l) {
    // --- MHA ---
    k_red1<<<256, 256, 0, stream>>>(x, part);
    k_red2<<<1, 256, 0, stream>>>(part, scal);
    mm_qkv<<<dim3(48, 16), 256, 0, stream>>>(
        x, Wqkv + (size_t)l * EDIM * 3 * EDIM, bqkv + (size_t)l * 3 * EDIM,
        g_mha + (size_t)l * EDIM, scal, qb, kb, vb);
    k_flash<<<dim3(8, 32), 256, 0, stream>>>(qb, kb, vb, y2);
    mm_g<1, 0><<<dim3(16, 16), 256, 0, stream>>>(
        y2, Wo + (size_t)l * EDIM * EDIM, bo + (size_t)l * EDIM, x,
        nullptr, nullptr, x, EDIM, EDIM, EDIM);
    // --- SwiGLU FFN ---
    k_red1<<<256, 256, 0, stream>>>(x, part);
    k_red2<<<1, 256, 0, stream>>>(part, scal);
    mm_w13<<<dim3(43, 16), 256, 0, stream>>>(
        x, W1 + (size_t)l * EDIM * DFFDIM, W3 + (size_t)l * EDIM * DFFDIM,
        b1 + (size_t)l * DFFDIM, b3 + (size_t)l * DFFDIM,
        g_ff + (size_t)l * EDIM, scal, big);
    mm_g<1, 0><<<dim3(16, 16), 256, 0, stream>>>(
        big, W2 + (size_t)l * DFFDIM * EDIM, b2 + (size_t)l * EDIM, x,
        nullptr, nullptr, x, EDIM, DPAD, DFFDIM);
  }

  // --- final RMS + vocab head (RMS fused into head A-staging) ---
  k_red1<<<256, 256, 0, stream>>>(x, part);
  k_red2<<<1, 256, 0, stream>>>(part, scal);
  mm_g<0, 1><<<dim3(127, 16), 256, 0, stream>>>(
      x, Wout, bout, nullptr, g_final, scal, out, VOCAB, EDIM, EDIM);
}

// Round 4
// 4306.931 us; speedup vs baseline: 3.9939x; 2.5635x over previous
//
#include <hip/hip_runtime.h>
#include <hip/hip_bf16.h>
#include <math.h>

#define EDIM   1024
#define TSEQ   512
#define NBATCH 2
#define NHEAD  16
#define HDIM   64
#define NLAYER 24
#define VOCAB  8124
#define DFFDIM 2730
#define DPAD   2752              // 43*64 padded SwiGLU width
#define MTOK   (NBATCH*TSEQ)     // 1024
#define NELEM  (MTOK*EDIM)
#define EPSF   1e-5f
#define SCALEF (1.0f/32.0f)
#define NEGBIG (-1e30f)

typedef __bf16 bf16x8 __attribute__((ext_vector_type(8)));
typedef __bf16 bf16x4 __attribute__((ext_vector_type(4)));
typedef float  f32x4  __attribute__((ext_vector_type(4)));

#define MFMA(a, b, c) __builtin_amdgcn_mfma_f32_16x16x32_bf16((a), (b), (c), 0, 0, 0)

// async global->LDS, 16B per lane. LDS dest must be wave-uniform base + lane*16.
__device__ __forceinline__ void gl_lds16(const __bf16* g, __bf16* l) {
  __builtin_amdgcn_global_load_lds(
      (const __attribute__((address_space(1))) void*)g,
      (__attribute__((address_space(3))) void*)l, 16, 0, 0);
}

// ---------------------------------------------------------------- embedding+PE
__global__ __launch_bounds__(256) void k_embed(const int* __restrict__ tok,
                                               const float* __restrict__ emb,
                                               float* __restrict__ x) {
  const int bt = blockIdx.x;
  const int t  = bt & (TSEQ - 1);
  const int tk = tok[bt];
  const float* er = emb + (size_t)tk * EDIM;
  float* xr = x + (size_t)bt * EDIM;
  for (int e = threadIdx.x * 4; e < EDIM; e += 256 * 4) {
    float4 v = *(const float4*)(er + e);
    float vv[4] = {v.x, v.y, v.z, v.w};
    float ou[4];
#pragma unroll
    for (int j = 0; j < 4; ++j) {
      int ee = e + j;
      int i2 = ee & ~1;
      float freq = expf(-(float)i2 * (9.210340371976184f / 1024.0f));
      float ang  = (float)t * freq;
      ou[j] = vv[j] + ((ee & 1) ? cosf(ang) : sinf(ang));
    }
    *(float4*)(xr + e) = make_float4(ou[0], ou[1], ou[2], ou[3]);
  }
}

// ------------------------------------------------- RMS reduce (+fold partials)
__global__ __launch_bounds__(256) void k_red1f(float* __restrict__ x,
                                               const float* __restrict__ p0,
                                               const float* __restrict__ p1,
                                               const float* __restrict__ bias,
                                               float* __restrict__ part) {
  float s = 0.f;
  const bool fold = (p0 != nullptr);
  for (int i = (blockIdx.x * 256 + threadIdx.x) * 4; i < NELEM; i += 256 * 256 * 4) {
    float4 v = *(const float4*)(x + i);
    if (fold) {
      float4 a = *(const float4*)(p0 + i);
      float4 b = *(const float4*)(p1 + i);
      float4 c = *(const float4*)(bias + (i & (EDIM - 1)));
      v.x += a.x + b.x + c.x; v.y += a.y + b.y + c.y;
      v.z += a.z + b.z + c.z; v.w += a.w + b.w + c.w;
      *(float4*)(x + i) = v;
    }
    s += v.x * v.x + v.y * v.y + v.z * v.z + v.w * v.w;
  }
#pragma unroll
  for (int o = 32; o > 0; o >>= 1) s += __shfl_down(s, o);
  __shared__ float sm[4];
  if ((threadIdx.x & 63) == 0) sm[threadIdx.x >> 6] = s;
  __syncthreads();
  if (threadIdx.x == 0) part[blockIdx.x] = sm[0] + sm[1] + sm[2] + sm[3];
}

__global__ __launch_bounds__(256) void k_red2(const float* __restrict__ part,
                                              float* __restrict__ scale) {
  float s = part[threadIdx.x];
#pragma unroll
  for (int o = 32; o > 0; o >>= 1) s += __shfl_down(s, o);
  __shared__ float sm[4];
  if ((threadIdx.x & 63) == 0) sm[threadIdx.x >> 6] = s;
  __syncthreads();
  if (threadIdx.x == 0) {
    float tot = sm[0] + sm[1] + sm[2] + sm[3];
    scale[0] = 1.0f / sqrtf(tot / (float)NELEM + EPSF);
  }
}

__global__ __launch_bounds__(256) void k_rms_bf(const float* __restrict__ x,
                                                const float* __restrict__ g,
                                                const float* __restrict__ scal,
                                                __bf16* __restrict__ y) {
  const float sc = scal[0];
  const int i = (blockIdx.x * 256 + threadIdx.x) * 4;
  float4 v  = *(const float4*)(x + i);
  float4 gv = *(const float4*)(g + (i & (EDIM - 1)));
  bf16x4 o = {(__bf16)(v.x * sc * gv.x), (__bf16)(v.y * sc * gv.y),
              (__bf16)(v.z * sc * gv.z), (__bf16)(v.w * sc * gv.w)};
  *(bf16x4*)(y + i) = o;
}

// ------------------------------------------------- weight convert + transpose
// src [K][N] f32  ->  dst [Npad][Kpad] bf16 (zero-padded)
__device__ __forceinline__ void conv_tile(const float* __restrict__ src,
                                          __bf16* __restrict__ dst,
                                          int K, int N, int Kpad, int tk, int tn) {
  __shared__ float st[64][65];
  const int k0 = tk << 6, n0 = tn << 6;
  const int tid = threadIdx.x;
  const int r0 = tid >> 4, c4 = (tid & 15) << 2;
#pragma unroll
  for (int i = 0; i < 4; ++i) {
    const int r = r0 + i * 16;
    const int k = k0 + r;
    float4 v = make_float4(0.f, 0.f, 0.f, 0.f);
    if (k < K) {
      const float* sp = src + (size_t)k * N + n0 + c4;
      if (n0 + c4 + 3 < N) v = *(const float4*)sp;
      else {
        if (n0 + c4 + 0 < N) v.x = sp[0];
        if (n0 + c4 + 1 < N) v.y = sp[1];
        if (n0 + c4 + 2 < N) v.z = sp[2];
        if (n0 + c4 + 3 < N) v.w = sp[3];
      }
    }
    st[r][c4 + 0] = v.x; st[r][c4 + 1] = v.y; st[r][c4 + 2] = v.z; st[r][c4 + 3] = v.w;
  }
  __syncthreads();
#pragma unroll
  for (int i = 0; i < 4; ++i) {
    const int rr = r0 + i * 16;   // n-local
    bf16x4 o = {(__bf16)st[c4 + 0][rr], (__bf16)st[c4 + 1][rr],
                (__bf16)st[c4 + 2][rr], (__bf16)st[c4 + 3][rr]};
    *(bf16x4*)&dst[(size_t)(n0 + rr) * Kpad + k0 + c4] = o;
  }
}

__global__ __launch_bounds__(256) void k_convL(const float* __restrict__ Wqkv,
                                               const float* __restrict__ Wo,
                                               const float* __restrict__ W1,
                                               const float* __restrict__ W3,
                                               const float* __restrict__ W2w,
                                               __bf16* qkvT, __bf16* woT,
                                               __bf16* w1T, __bf16* w3T, __bf16* w2T) {
  const int b = blockIdx.x;
  if (b < 768)       { conv_tile(Wqkv, qkvT, 1024, 3072, 1024, b / 48, b % 48); }
  else if (b < 1024) { int t = b - 768;  conv_tile(Wo,  woT,  1024, 1024, 1024, t / 16, t % 16); }
  else if (b < 1712) { int t = b - 1024; conv_tile(W1,  w1T,  1024, 2730, 1024, t / 43, t % 43); }
  else if (b < 2400) { int t = b - 1712; conv_tile(W3,  w3T,  1024, 2730, 1024, t / 43, t % 43); }
  else               { int t = b - 2400; conv_tile(W2w, w2T,  2730, 1024, 2752, t / 16, t % 16); }
}

__global__ __launch_bounds__(256) void k_convH(const float* __restrict__ Wout,
                                               __bf16* __restrict__ WoutT) {
  conv_tile(Wout, WoutT, 1024, VOCAB, 1024, blockIdx.x / 127, blockIdx.x % 127);
}

// ================================================================ MFMA GEMM
// A [M][lda] bf16 row-major, B [N][ldb] bf16 (pre-transposed). BN=64, BK=64.
// LDS linear [kb][row][8] layouts fed by global_load_lds (lane-linear deposits).
// 4 waves, wave tile (BM/4)x64. 2-phase pipeline, double-buffered LDS.
// MODE: 0=qkv scatter  1=split-K partial (f32, no bias)  2=SwiGLU dual  3=head
template <int BM, int MODE>
__global__ __launch_bounds__(256) void mm(
    const __bf16* __restrict__ A, const __bf16* __restrict__ B0w,
    const __bf16* __restrict__ B1w,
    const float* __restrict__ bias0, const float* __restrict__ bias1,
    float* __restrict__ po, __bf16* __restrict__ ob,
    __bf16* __restrict__ qout, __bf16* __restrict__ kout, __bf16* __restrict__ vout,
    int N, int lda, int ldb, int Ktot) {
  constexpr int DUAL = (MODE == 2) ? 2 : 1;
  constexpr int FM = BM / 64;          // m-frags per wave
  constexpr int NA = BM / 32;          // A deposits per thread
  __shared__ __bf16 As[2][8][BM][8];
  __shared__ __bf16 Bs[2][DUAL][8][64][8];
  const int tid = threadIdx.x, lane = tid & 63, wave = tid >> 6;
  const int m0 = blockIdx.y * BM, n0 = blockIdx.x << 6;
  const int wrow0 = wave * (BM / 4);
  const int lr = lane & 15, kh = lane >> 4;

  const int ktiles = Ktot >> 6;
  const int nt0 = (ktiles + gridDim.z - 1) / gridDim.z;
  const int tbeg = blockIdx.z * nt0;
  const int tend = (ktiles < tbeg + nt0) ? ktiles : (tbeg + nt0);
  const int nt = tend - tbeg;

  f32x4 acc[DUAL][FM][4];
#pragma unroll
  for (int d = 0; d < DUAL; ++d)
#pragma unroll
    for (int mi = 0; mi < FM; ++mi)
#pragma unroll
      for (int ni = 0; ni < 4; ++ni) acc[d][mi][ni] = (f32x4){0.f, 0.f, 0.f, 0.f};

  auto STAGE = [&](int buf, int t) {
    const int k0 = (tbeg + t) << 6;
#pragma unroll
    for (int i = 0; i < NA; ++i) {
      const int d = i * 256 + tid;
      const int kb2 = d / BM, row = d % BM;
      gl_lds16(A + (size_t)(m0 + row) * lda + k0 + kb2 * 8, &As[buf][kb2][row][0]);
    }
#pragma unroll
    for (int i = 0; i < 2; ++i) {
      const int d = i * 256 + tid;
      const int kb2 = d >> 6, col = d & 63;
      gl_lds16(B0w + (size_t)(n0 + col) * ldb + k0 + kb2 * 8, &Bs[buf][0][kb2][col][0]);
      if (MODE == 2)
        gl_lds16(B1w + (size_t)(n0 + col) * ldb + k0 + kb2 * 8, &Bs[buf][DUAL - 1][kb2][col][0]);
    }
  };
  auto COMP = [&](int buf) {
#pragma unroll
    for (int ks = 0; ks < 2; ++ks) {
      const int kidx = ks * 4 + kh;
      bf16x8 af[FM];
#pragma unroll
      for (int mi = 0; mi < FM; ++mi)
        af[mi] = *(const bf16x8*)&As[buf][kidx][wrow0 + mi * 16 + lr][0];
#pragma unroll
      for (int d = 0; d < DUAL; ++d)
#pragma unroll
        for (int ni = 0; ni < 4; ++ni) {
          bf16x8 bfr = *(const bf16x8*)&Bs[buf][d][kidx][ni * 16 + lr][0];
#pragma unroll
          for (int mi = 0; mi < FM; ++mi)
            acc[d][mi][ni] = MFMA(af[mi], bfr, acc[d][mi][ni]);
        }
    }
  };

  STAGE(0, 0);
  __syncthreads();
  for (int t = 0; t + 1 < nt; ++t) {
    STAGE((t + 1) & 1, t + 1);
    COMP(t & 1);
    __syncthreads();
  }
  COMP((nt - 1) & 1);

#pragma unroll
  for (int mi = 0; mi < FM; ++mi)
#pragma unroll
    for (int ni = 0; ni < 4; ++ni) {
      const int col = n0 + ni * 16 + lr;
      if (MODE == 0) {
        const float bs = bias0[col];
        const int h = col / (3 * HDIM);
        const int rsel = (col >> 6) % 3;
        const int s2 = col & (HDIM - 1);
#pragma unroll
        for (int j = 0; j < 4; ++j) {
          const int row = m0 + wrow0 + mi * 16 + (kh << 2) + j;
          const int b = row >> 9, t = row & (TSEQ - 1);
          const float v = acc[0][mi][ni][j] + bs;
          if (rsel == 0)      qout[((size_t)(b * NHEAD + h) * TSEQ + t) * HDIM + s2] = (__bf16)v;
          else if (rsel == 1) kout[((size_t)(b * NHEAD + h) * TSEQ + t) * HDIM + s2] = (__bf16)v;
          else                vout[((size_t)(b * NHEAD + h) * HDIM + s2) * TSEQ + t] = (__bf16)v;
        }
      } else if (MODE == 1) {
        float* pz = po + (size_t)blockIdx.z * MTOK * EDIM;
#pragma unroll
        for (int j = 0; j < 4; ++j) {
          const int row = m0 + wrow0 + mi * 16 + (kh << 2) + j;
          pz[(size_t)row * EDIM + col] = acc[0][mi][ni][j];
        }
      } else if (MODE == 2) {
        const bool ok = col < N;
        const float bb1 = ok ? bias0[col] : 0.f;
        const float bb3 = ok ? bias1[col] : 0.f;
#pragma unroll
        for (int j = 0; j < 4; ++j) {
          const int row = m0 + wrow0 + mi * 16 + (kh << 2) + j;
          const float a1v = acc[0][mi][ni][j] + bb1;
          const float a3v = acc[DUAL - 1][mi][ni][j] + bb3;
          const float v = a1v * (1.0f / (1.0f + __expf(-a1v))) * a3v;
          ob[(size_t)row * DPAD + col] = (__bf16)v;
        }
      } else {  // MODE 3: head
        if (col < N) {
          const float bs = bias0[col];
#pragma unroll
          for (int j = 0; j < 4; ++j) {
            const int row = m0 + wrow0 + mi * 16 + (kh << 2) + j;
            po[(size_t)row * N + col] = acc[0][mi][ni][j] + bs;
          }
        }
      }
    }
}

// ------------------------------------------------- flash attention (bf16 in)
__global__ __launch_bounds__(256) void k_flash(const __bf16* __restrict__ qbuf,
                                               const __bf16* __restrict__ kbuf,
                                               const __bf16* __restrict__ vbufT,
                                               __bf16* __restrict__ y2) {
  const int qt = blockIdx.x, bh = blockIdx.y;
  const int b = bh >> 4, h = bh & 15;
  const int m0 = qt << 6;
  const __bf16* qp = qbuf  + (size_t)bh * TSEQ * HDIM;
  const __bf16* kp = kbuf  + (size_t)bh * TSEQ * HDIM;
  const __bf16* vp = vbufT + (size_t)bh * HDIM * TSEQ;   // [s][t]
  __shared__ __bf16 Qs[8][64][8], Ks[8][64][8], Vs[8][64][8], Ps[8][64][8];
  __shared__ float wmax[2][64], wsum[2][64];
  const int tid = threadIdx.x, lane = tid & 63, wave = tid >> 6;
  const int wm = (wave >> 1) << 5, wn = (wave & 1) << 5;
  const int lr = lane & 15, kh = lane >> 4;

  // stage Q once (512 deposits)
#pragma unroll
  for (int i = 0; i < 2; ++i) {
    const int d = i * 256 + tid;
    const int kb2 = d >> 6, row = d & 63;
    gl_lds16(qp + (size_t)(m0 + row) * HDIM + kb2 * 8, &Qs[kb2][row][0]);
  }
  float m_[2][4], l_[2][4];
#pragma unroll
  for (int mi = 0; mi < 2; ++mi)
#pragma unroll
    for (int j = 0; j < 4; ++j) { m_[mi][j] = NEGBIG; l_[mi][j] = 0.f; }
  f32x4 o00 = {0,0,0,0}, o01 = {0,0,0,0}, o10 = {0,0,0,0}, o11 = {0,0,0,0};

  for (int kt = 0; kt <= qt; ++kt) {
    const int n0 = kt << 6;
    __syncthreads();  // B0: previous tile's LDS reads done
#pragma unroll
    for (int i = 0; i < 2; ++i) {
      const int d = i * 256 + tid;
      const int kb2 = d >> 6, row = d & 63;
      gl_lds16(kp + (size_t)(n0 + row) * HDIM + kb2 * 8, &Ks[kb2][row][0]);
      gl_lds16(vp + (size_t)row * TSEQ + n0 + kb2 * 8, &Vs[kb2][row][0]);
    }
    __syncthreads();  // B1: K/V (and Q on iter 0) ready

    f32x4 s00 = {0,0,0,0}, s01 = {0,0,0,0}, s10 = {0,0,0,0}, s11 = {0,0,0,0};
#pragma unroll
    for (int ks = 0; ks < 2; ++ks) {
      const int kidx = ks * 4 + kh;
      bf16x8 a0 = *(const bf16x8*)&Qs[kidx][wm + lr][0];
      bf16x8 a1 = *(const bf16x8*)&Qs[kidx][wm + 16 + lr][0];
      bf16x8 b0 = *(const bf16x8*)&Ks[kidx][wn + lr][0];
      bf16x8 b1 = *(const bf16x8*)&Ks[kidx][wn + 16 + lr][0];
      s00 = MFMA(a0, b0, s00); s01 = MFMA(a0, b1, s01);
      s10 = MFMA(a1, b0, s10); s11 = MFMA(a1, b1, s11);
    }
    float pv_[2][2][4];
#pragma unroll
    for (int mi = 0; mi < 2; ++mi)
#pragma unroll
      for (int j = 0; j < 4; ++j) {
        const int grow = m0 + wm + mi * 16 + (kh << 2) + j;
        float best = NEGBIG;
#pragma unroll
        for (int ni = 0; ni < 2; ++ni) {
          f32x4 sfr = (mi == 0) ? (ni == 0 ? s00 : s01) : (ni == 0 ? s10 : s11);
          const int gcol = n0 + wn + ni * 16 + lr;
          float t = sfr[j] * SCALEF;
          if (gcol > grow) t = NEGBIG;
          pv_[mi][ni][j] = t;
          best = fmaxf(best, t);
        }
        float v = best;
        v = fmaxf(v, __shfl_xor(v, 1)); v = fmaxf(v, __shfl_xor(v, 2));
        v = fmaxf(v, __shfl_xor(v, 4)); v = fmaxf(v, __shfl_xor(v, 8));
        wmax[wave & 1][wm + mi * 16 + (kh << 2) + j] = v;
      }
    __syncthreads();  // B2: wmax visible

    float alpha[2][4];
#pragma unroll
    for (int mi = 0; mi < 2; ++mi)
#pragma unroll
      for (int j = 0; j < 4; ++j) {
        const int rl = wm + mi * 16 + (kh << 2) + j;
        const float tmax = fmaxf(wmax[0][rl], wmax[1][rl]);
        const float mn = fmaxf(m_[mi][j], tmax);
        alpha[mi][j] = __expf(m_[mi][j] - mn);
        m_[mi][j] = mn;
        float rs = 0.f;
#pragma unroll
        for (int ni = 0; ni < 2; ++ni) {
          const float p = __expf(pv_[mi][ni][j] - mn);
          pv_[mi][ni][j] = p;
          rs += p;
        }
        rs += __shfl_xor(rs, 1); rs += __shfl_xor(rs, 2);
        rs += __shfl_xor(rs, 4); rs += __shfl_xor(rs, 8);
        wsum[wave & 1][rl] = rs;
      }
#pragma unroll
    for (int mi = 0; mi < 2; ++mi)
#pragma unroll
      for (int ni = 0; ni < 2; ++ni)
#pragma unroll
        for (int j = 0; j < 4; ++j) {
          const int prow = wm + mi * 16 + (kh << 2) + j;
          const int pcol = wn + ni * 16 + lr;
          Ps[pcol >> 3][prow][pcol & 7] = (__bf16)pv_[mi][ni][j];
        }
    __syncthreads();  // B3: wsum & Ps visible

#pragma unroll
    for (int mi = 0; mi < 2; ++mi)
#pragma unroll
      for (int j = 0; j < 4; ++j) {
        const int rl = wm + mi * 16 + (kh << 2) + j;
        l_[mi][j] = l_[mi][j] * alpha[mi][j] + wsum[0][rl] + wsum[1][rl];
      }
#pragma unroll
    for (int j = 0; j < 4; ++j) {
      o00[j] *= alpha[0][j]; o01[j] *= alpha[0][j];
      o10[j] *= alpha[1][j]; o11[j] *= alpha[1][j];
    }
#pragma unroll
    for (int ks = 0; ks < 2; ++ks) {
      const int kidx = ks * 4 + kh;
      bf16x8 a0 = *(const bf16x8*)&Ps[kidx][wm + lr][0];
      bf16x8 a1 = *(const bf16x8*)&Ps[kidx][wm + 16 + lr][0];
      bf16x8 b0 = *(const bf16x8*)&Vs[kidx][wn + lr][0];
      bf16x8 b1 = *(const bf16x8*)&Vs[kidx][wn + 16 + lr][0];
      o00 = MFMA(a0, b0, o00); o01 = MFMA(a0, b1, o01);
      o10 = MFMA(a1, b0, o10); o11 = MFMA(a1, b1, o11);
    }
  }

#pragma unroll
  for (int mi = 0; mi < 2; ++mi)
#pragma unroll
    for (int ni = 0; ni < 2; ++ni) {
      f32x4 oo = (mi == 0) ? (ni == 0 ? o00 : o01) : (ni == 0 ? o10 : o11);
      const int col = wn + ni * 16 + lr;
#pragma unroll
      for (int j = 0; j < 4; ++j) {
        const int row = m0 + wm + mi * 16 + (kh << 2) + j;
        y2[((size_t)(b * TSEQ) + row) * EDIM + h * HDIM + col] = (__bf16)(oo[j] / l_[mi][j]);
      }
    }
}

// ---------------------------------------------------------------- launcher
extern "C" void kernel_launch(void* const* d_in, const int* in_sizes, int n_in,
                              void* d_out, int out_size, void* d_ws, size_t ws_size,
                              hipStream_t stream) {
  const int*   tokens  = (const int*)d_in[0];
  const float* emb     = (const float*)d_in[1];
  const float* Wqkv    = (const float*)d_in[2];
  const float* bqkv    = (const float*)d_in[3];
  const float* Wo      = (const float*)d_in[4];
  const float* bo      = (const float*)d_in[5];
  const float* W1      = (const float*)d_in[6];
  const float* b1      = (const float*)d_in[7];
  const float* W3      = (const float*)d_in[8];
  const float* b3      = (const float*)d_in[9];
  const float* W2w     = (const float*)d_in[10];
  const float* b2      = (const float*)d_in[11];
  const float* g_mha   = (const float*)d_in[12];
  const float* g_ff    = (const float*)d_in[13];
  const float* g_final = (const float*)d_in[14];
  const float* Wout    = (const float*)d_in[15];
  const float* bout    = (const float*)d_in[16];
  float* out = (float*)d_out;

  char* base = (char*)d_ws;
  size_t off = 0;
  auto alloc = [&](size_t bytes) { char* p = base + off; off = (off + bytes + 255) & ~(size_t)255; return p; };
  float*  x    = (float*)alloc(4u << 20);
  float*  part = (float*)alloc(2048);
  float*  scal = (float*)alloc(256);
  __bf16* ybf  = (__bf16*)alloc(2u << 20);
  __bf16* qbf  = (__bf16*)alloc(2u << 20);
  __bf16* kbf  = (__bf16*)alloc(2u << 20);
  __bf16* vbT  = (__bf16*)alloc(2u << 20);
  __bf16* y2bf = (__bf16*)alloc(2u << 20);
  __bf16* ubf  = (__bf16*)alloc((size_t)MTOK * DPAD * 2);
  float*  pbuf = (float*)alloc((size_t)2 * MTOK * EDIM * 4);
  __bf16* qkvT = (__bf16*)alloc((size_t)3072 * 1024 * 2);
  __bf16* woT  = (__bf16*)alloc((size_t)1024 * 1024 * 2);
  __bf16* w1T  = (__bf16*)alloc((size_t)2752 * 1024 * 2);
  __bf16* w3T  = (__bf16*)alloc((size_t)2752 * 1024 * 2);
  __bf16* w2T  = (__bf16*)alloc((size_t)1024 * 2752 * 2);
  __bf16* WoutT = qkvT;   // alias: head conv happens after last layer's GEMMs (needs 16.6MB <= 19MB)

  k_embed<<<MTOK, 256, 0, stream>>>(tokens, emb, x);

  const float* pend_bias = nullptr;   // partials pending fold into x
  for (int l = 0; l < NLAYER; ++l) {
    k_convL<<<3088, 256, 0, stream>>>(
        Wqkv + (size_t)l * EDIM * 3 * EDIM, Wo + (size_t)l * EDIM * EDIM,
        W1 + (size_t)l * EDIM * DFFDIM, W3 + (size_t)l * EDIM * DFFDIM,
        W2w + (size_t)l * DFFDIM * EDIM, qkvT, woT, w1T, w3T, w2T);
    // --- MHA ---
    k_red1f<<<256, 256, 0, stream>>>(x, pend_bias ? pbuf : nullptr,
                                     pbuf + (size_t)MTOK * EDIM, pend_bias, part);
    k_red2<<<1, 256, 0, stream>>>(part, scal);
    k_rms_bf<<<1024, 256, 0, stream>>>(x, g_mha + (size_t)l * EDIM, scal, ybf);
    mm<128, 0><<<dim3(48, 8, 1), 256, 0, stream>>>(
        ybf, qkvT, nullptr, bqkv + (size_t)l * 3 * EDIM, nullptr,
        nullptr, nullptr, qbf, kbf, vbT, 3072, 1024, 1024, 1024);
    k_flash<<<dim3(8, 32), 256, 0, stream>>>(qbf, kbf, vbT, y2bf);
    mm<64, 1><<<dim3(16, 16, 2), 256, 0, stream>>>(
        y2bf, woT, nullptr, nullptr, nullptr,
        pbuf, nullptr, nullptr, nullptr, nullptr, 1024, 1024, 1024, 1024);
    // --- SwiGLU FFN ---
    k_red1f<<<256, 256, 0, stream>>>(x, pbuf, pbuf + (size_t)MTOK * EDIM,
                                     bo + (size_t)l * EDIM, part);
    k_red2<<<1, 256, 0, stream>>>(part, scal);
    k_rms_bf<<<1024, 256, 0, stream>>>(x, g_ff + (size_t)l * EDIM, scal, ybf);
    mm<128, 2><<<dim3(43, 8, 1), 256, 0, stream>>>(
        ybf, w1T, w3T, b1 + (size_t)l * DFFDIM, b3 + (size_t)l * DFFDIM,
        nullptr, ubf, nullptr, nullptr, nullptr, DFFDIM, 1024, 1024, 1024);
    mm<64, 1><<<dim3(16, 16, 2), 256, 0, stream>>>(
        ubf, w2T, nullptr, nullptr, nullptr,
        pbuf, nullptr, nullptr, nullptr, nullptr, 1024, DPAD, 2752, 2752);
    pend_bias = b2 + (size_t)l * EDIM;
  }

  // --- final RMS + vocab head ---
  k_red1f<<<256, 256, 0, stream>>>(x, pbuf, pbuf + (size_t)MTOK * EDIM, pend_bias, part);
  k_red2<<<1, 256, 0, stream>>>(part, scal);
  k_rms_bf<<<1024, 256, 0, stream>>>(x, g_final, scal, ybf);
  k_convH<<<2032, 256, 0, stream>>>(Wout, WoutT);
  mm<128, 3><<<dim3(127, 8, 1), 256, 0, stream>>>(
      ybf, WoutT, nullptr, bout, nullptr,
      out, nullptr, nullptr, nullptr, nullptr, VOCAB, 1024, 1024, 1024);
}

// Round 5
// 4021.058 us; speedup vs baseline: 4.2778x; 1.0711x over previous
//
#include <hip/hip_runtime.h>
#include <hip/hip_bf16.h>
#include <math.h>

#define EDIM   1024
#define TSEQ   512
#define NBATCH 2
#define NHEAD  16
#define HDIM   64
#define NLAYER 24
#define VOCAB  8124
#define DFFDIM 2730
#define DPAD   2752              // 43*64 padded SwiGLU width
#define MTOK   (NBATCH*TSEQ)     // 1024
#define NELEM  (MTOK*EDIM)
#define EPSF   1e-5f
#define SCALEF (1.0f/32.0f)
#define NEGBIG (-1e30f)

typedef __bf16 bf16x8 __attribute__((ext_vector_type(8)));
typedef __bf16 bf16x4 __attribute__((ext_vector_type(4)));
typedef float  f32x4  __attribute__((ext_vector_type(4)));

#define MFMA(a, b, c) __builtin_amdgcn_mfma_f32_16x16x32_bf16((a), (b), (c), 0, 0, 0)

// async global->LDS, 16B per lane. LDS dest must be wave-uniform base + lane*16.
__device__ __forceinline__ void gl_lds16(const __bf16* g, __bf16* l) {
  __builtin_amdgcn_global_load_lds(
      (const __attribute__((address_space(1))) void*)g,
      (__attribute__((address_space(3))) void*)l, 16, 0, 0);
}

template <int N> __device__ __forceinline__ void vmwait() {
  asm volatile("s_waitcnt vmcnt(%0)" :: "n"(N) : "memory");
}
__device__ __forceinline__ void lgkm_barrier() {
  asm volatile("s_waitcnt lgkmcnt(0)" ::: "memory");
  __builtin_amdgcn_s_barrier();
}

// ---------------------------------------------------------------- embedding+PE
__global__ __launch_bounds__(256) void k_embed(const int* __restrict__ tok,
                                               const float* __restrict__ emb,
                                               float* __restrict__ x) {
  const int bt = blockIdx.x;
  const int t  = bt & (TSEQ - 1);
  const int tk = tok[bt];
  const float* er = emb + (size_t)tk * EDIM;
  float* xr = x + (size_t)bt * EDIM;
  for (int e = threadIdx.x * 4; e < EDIM; e += 256 * 4) {
    float4 v = *(const float4*)(er + e);
    float vv[4] = {v.x, v.y, v.z, v.w};
    float ou[4];
#pragma unroll
    for (int j = 0; j < 4; ++j) {
      int ee = e + j;
      int i2 = ee & ~1;
      float freq = expf(-(float)i2 * (9.210340371976184f / 1024.0f));
      float ang  = (float)t * freq;
      ou[j] = vv[j] + ((ee & 1) ? cosf(ang) : sinf(ang));
    }
    *(float4*)(xr + e) = make_float4(ou[0], ou[1], ou[2], ou[3]);
  }
}

// ------------------------------------------------- RMS reduce (+fold partials)
__global__ __launch_bounds__(256) void k_red1f(float* __restrict__ x,
                                               const float* __restrict__ p0,
                                               const float* __restrict__ p1,
                                               const float* __restrict__ bias,
                                               float* __restrict__ part) {
  float s = 0.f;
  const bool fold = (p0 != nullptr);
  for (int i = (blockIdx.x * 256 + threadIdx.x) * 4; i < NELEM; i += 256 * 256 * 4) {
    float4 v = *(const float4*)(x + i);
    if (fold) {
      float4 a = *(const float4*)(p0 + i);
      float4 b = *(const float4*)(p1 + i);
      float4 c = *(const float4*)(bias + (i & (EDIM - 1)));
      v.x += a.x + b.x + c.x; v.y += a.y + b.y + c.y;
      v.z += a.z + b.z + c.z; v.w += a.w + b.w + c.w;
      *(float4*)(x + i) = v;
    }
    s += v.x * v.x + v.y * v.y + v.z * v.z + v.w * v.w;
  }
#pragma unroll
  for (int o = 32; o > 0; o >>= 1) s += __shfl_down(s, o);
  __shared__ float sm[4];
  if ((threadIdx.x & 63) == 0) sm[threadIdx.x >> 6] = s;
  __syncthreads();
  if (threadIdx.x == 0) part[blockIdx.x] = sm[0] + sm[1] + sm[2] + sm[3];
}

// --- fused: reduce part[256] -> scale, then y = bf16(x * sc * g)
__global__ __launch_bounds__(256) void k_rms2(const float* __restrict__ x,
                                              const float* __restrict__ g,
                                              const float* __restrict__ part,
                                              __bf16* __restrict__ y) {
  float s = part[threadIdx.x];
#pragma unroll
  for (int o = 32; o > 0; o >>= 1) s += __shfl_down(s, o);
  __shared__ float sm[4];
  if ((threadIdx.x & 63) == 0) sm[threadIdx.x >> 6] = s;
  __syncthreads();
  const float sc = 1.0f / sqrtf((sm[0] + sm[1] + sm[2] + sm[3]) / (float)NELEM + EPSF);
  const int i = (blockIdx.x * 256 + threadIdx.x) * 4;
  float4 v  = *(const float4*)(x + i);
  float4 gv = *(const float4*)(g + (i & (EDIM - 1)));
  bf16x4 o4 = {(__bf16)(v.x * sc * gv.x), (__bf16)(v.y * sc * gv.y),
               (__bf16)(v.z * sc * gv.z), (__bf16)(v.w * sc * gv.w)};
  *(bf16x4*)(y + i) = o4;
}

// ------------------------------------------------- weight convert + transpose
// src [K][N] f32  ->  dst [Npad][Kpad] bf16 (zero-padded)
__device__ __forceinline__ void conv_tile(const float* __restrict__ src,
                                          __bf16* __restrict__ dst,
                                          int K, int N, int Kpad, int tk, int tn) {
  __shared__ float st[64][65];
  const int k0 = tk << 6, n0 = tn << 6;
  const int tid = threadIdx.x;
  const int r0 = tid >> 4, c4 = (tid & 15) << 2;
#pragma unroll
  for (int i = 0; i < 4; ++i) {
    const int r = r0 + i * 16;
    const int k = k0 + r;
    float4 v = make_float4(0.f, 0.f, 0.f, 0.f);
    if (k < K) {
      const float* sp = src + (size_t)k * N + n0 + c4;
      if (n0 + c4 + 3 < N) v = *(const float4*)sp;
      else {
        if (n0 + c4 + 0 < N) v.x = sp[0];
        if (n0 + c4 + 1 < N) v.y = sp[1];
        if (n0 + c4 + 2 < N) v.z = sp[2];
        if (n0 + c4 + 3 < N) v.w = sp[3];
      }
    }
    st[r][c4 + 0] = v.x; st[r][c4 + 1] = v.y; st[r][c4 + 2] = v.z; st[r][c4 + 3] = v.w;
  }
  __syncthreads();
#pragma unroll
  for (int i = 0; i < 4; ++i) {
    const int rr = r0 + i * 16;   // n-local
    bf16x4 o = {(__bf16)st[c4 + 0][rr], (__bf16)st[c4 + 1][rr],
                (__bf16)st[c4 + 2][rr], (__bf16)st[c4 + 3][rr]};
    *(bf16x4*)&dst[(size_t)(n0 + rr) * Kpad + k0 + c4] = o;
  }
}

__global__ __launch_bounds__(256) void k_convL(const float* __restrict__ Wqkv,
                                               const float* __restrict__ Wo,
                                               const float* __restrict__ W1,
                                               const float* __restrict__ W3,
                                               const float* __restrict__ W2w,
                                               __bf16* qkvT, __bf16* woT,
                                               __bf16* w1T, __bf16* w3T, __bf16* w2T) {
  const int b = blockIdx.x;
  if (b < 768)       { conv_tile(Wqkv, qkvT, 1024, 3072, 1024, b / 48, b % 48); }
  else if (b < 1024) { int t = b - 768;  conv_tile(Wo,  woT,  1024, 1024, 1024, t / 16, t % 16); }
  else if (b < 1712) { int t = b - 1024; conv_tile(W1,  w1T,  1024, 2730, 1024, t / 43, t % 43); }
  else if (b < 2400) { int t = b - 1712; conv_tile(W3,  w3T,  1024, 2730, 1024, t / 43, t % 43); }
  else               { int t = b - 2400; conv_tile(W2w, w2T,  2730, 1024, 2752, t / 16, t % 16); }
}

__global__ __launch_bounds__(256) void k_convH(const float* __restrict__ Wout,
                                               __bf16* __restrict__ WoutT) {
  conv_tile(Wout, WoutT, 1024, VOCAB, 1024, blockIdx.x / 127, blockIdx.x % 127);
}

// ================================================================ MFMA GEMM
// A [M][lda] bf16 row-major, B [N][ldb] bf16 (pre-transposed). BN=64, BK=64.
// global_load_lds staging, double-buffered LDS, COUNTED vmcnt (prefetch stays
// in flight across the raw s_barrier — no drain-0 in the main loop).
// MODE: 0=qkv scatter  1=split-K partial (f32, no bias)  2=SwiGLU dual  3=head
template <int BM, int MODE>
__global__ __launch_bounds__(256) void mm(
    const __bf16* __restrict__ A, const __bf16* __restrict__ B0w,
    const __bf16* __restrict__ B1w,
    const float* __restrict__ bias0, const float* __restrict__ bias1,
    float* __restrict__ po, __bf16* __restrict__ ob,
    __bf16* __restrict__ qout, __bf16* __restrict__ kout, __bf16* __restrict__ vout,
    int N, int lda, int ldb, int Ktot) {
  constexpr int DUAL = (MODE == 2) ? 2 : 1;
  constexpr int FM = BM / 64;          // m-frags per wave
  constexpr int NA = BM / 32;          // A deposits per thread
  constexpr int LOADS = NA + 2 * DUAL; // gload_lds per thread per STAGE
  __shared__ __bf16 As[2][8][BM][8];
  __shared__ __bf16 Bs[2][DUAL][8][64][8];
  const int tid = threadIdx.x, lane = tid & 63, wave = tid >> 6;
  const int m0 = blockIdx.y * BM, n0 = blockIdx.x << 6;
  const int wrow0 = wave * (BM / 4);
  const int lr = lane & 15, kh = lane >> 4;

  const int ktiles = Ktot >> 6;
  const int nt0 = (ktiles + gridDim.z - 1) / gridDim.z;
  const int tbeg = blockIdx.z * nt0;
  const int tend = (ktiles < tbeg + nt0) ? ktiles : (tbeg + nt0);
  const int nt = tend - tbeg;

  f32x4 acc[DUAL][FM][4];
#pragma unroll
  for (int d = 0; d < DUAL; ++d)
#pragma unroll
    for (int mi = 0; mi < FM; ++mi)
#pragma unroll
      for (int ni = 0; ni < 4; ++ni) acc[d][mi][ni] = (f32x4){0.f, 0.f, 0.f, 0.f};

  auto STAGE = [&](int buf, int t) {
    const int k0 = (tbeg + t) << 6;
#pragma unroll
    for (int i = 0; i < NA; ++i) {
      const int d = i * 256 + tid;
      const int kb2 = d / BM, row = d % BM;
      gl_lds16(A + (size_t)(m0 + row) * lda + k0 + kb2 * 8, &As[buf][kb2][row][0]);
    }
#pragma unroll
    for (int i = 0; i < 2; ++i) {
      const int d = i * 256 + tid;
      const int kb2 = d >> 6, col = d & 63;
      gl_lds16(B0w + (size_t)(n0 + col) * ldb + k0 + kb2 * 8, &Bs[buf][0][kb2][col][0]);
      if (MODE == 2)
        gl_lds16(B1w + (size_t)(n0 + col) * ldb + k0 + kb2 * 8, &Bs[buf][DUAL - 1][kb2][col][0]);
    }
  };
  auto COMP = [&](int buf) {
#pragma unroll
    for (int ks = 0; ks < 2; ++ks) {
      const int kidx = ks * 4 + kh;
      bf16x8 af[FM];
#pragma unroll
      for (int mi = 0; mi < FM; ++mi)
        af[mi] = *(const bf16x8*)&As[buf][kidx][wrow0 + mi * 16 + lr][0];
#pragma unroll
      for (int d = 0; d < DUAL; ++d)
#pragma unroll
        for (int ni = 0; ni < 4; ++ni) {
          bf16x8 bfr = *(const bf16x8*)&Bs[buf][d][kidx][ni * 16 + lr][0];
#pragma unroll
          for (int mi = 0; mi < FM; ++mi)
            acc[d][mi][ni] = MFMA(af[mi], bfr, acc[d][mi][ni]);
        }
    }
  };

  STAGE(0, 0);
  int cur = 0;
  for (int t = 0; t < nt - 1; ++t) {
    STAGE(cur ^ 1, t + 1);          // issue next tile; stays in flight
    vmwait<LOADS>();                // own tile-t loads retired
    __builtin_amdgcn_s_barrier();   // all waves: tile t resident
    COMP(cur);
    __builtin_amdgcn_s_barrier();   // all waves done reading buf before overwrite
    cur ^= 1;
  }
  vmwait<0>();
  __builtin_amdgcn_s_barrier();
  COMP(cur);

#pragma unroll
  for (int mi = 0; mi < FM; ++mi)
#pragma unroll
    for (int ni = 0; ni < 4; ++ni) {
      const int col = n0 + ni * 16 + lr;
      if (MODE == 0) {
        const float bs = bias0[col];
        const int h = col / (3 * HDIM);
        const int rsel = (col >> 6) % 3;
        const int s2 = col & (HDIM - 1);
#pragma unroll
        for (int j = 0; j < 4; ++j) {
          const int row = m0 + wrow0 + mi * 16 + (kh << 2) + j;
          const int b = row >> 9, t = row & (TSEQ - 1);
          const float v = acc[0][mi][ni][j] + bs;
          if (rsel == 0)      qout[((size_t)(b * NHEAD + h) * TSEQ + t) * HDIM + s2] = (__bf16)v;
          else if (rsel == 1) kout[((size_t)(b * NHEAD + h) * TSEQ + t) * HDIM + s2] = (__bf16)v;
          else                vout[((size_t)(b * NHEAD + h) * HDIM + s2) * TSEQ + t] = (__bf16)v;
        }
      } else if (MODE == 1) {
        float* pz = po + (size_t)blockIdx.z * MTOK * EDIM;
#pragma unroll
        for (int j = 0; j < 4; ++j) {
          const int row = m0 + wrow0 + mi * 16 + (kh << 2) + j;
          pz[(size_t)row * EDIM + col] = acc[0][mi][ni][j];
        }
      } else if (MODE == 2) {
        const bool ok = col < N;
        const float bb1 = ok ? bias0[col] : 0.f;
        const float bb3 = ok ? bias1[col] : 0.f;
#pragma unroll
        for (int j = 0; j < 4; ++j) {
          const int row = m0 + wrow0 + mi * 16 + (kh << 2) + j;
          const float a1v = acc[0][mi][ni][j] + bb1;
          const float a3v = acc[DUAL - 1][mi][ni][j] + bb3;
          const float v = a1v * (1.0f / (1.0f + __expf(-a1v))) * a3v;
          ob[(size_t)row * DPAD + col] = (__bf16)v;
        }
      } else {  // MODE 3: head
        if (col < N) {
          const float bs = bias0[col];
#pragma unroll
          for (int j = 0; j < 4; ++j) {
            const int row = m0 + wrow0 + mi * 16 + (kh << 2) + j;
            po[(size_t)row * N + col] = acc[0][mi][ni][j] + bs;
          }
        }
      }
    }
}

// ------------------------------------------------- flash attention (bf16 in)
// Double-buffered K/V, counted vmcnt prefetch; softmax barriers are
// lgkmcnt-only so in-flight K/V loads are never drained mid-iteration.
__global__ __launch_bounds__(256) void k_flash(const __bf16* __restrict__ qbuf,
                                               const __bf16* __restrict__ kbuf,
                                               const __bf16* __restrict__ vbufT,
                                               __bf16* __restrict__ y2) {
  const int qt = blockIdx.x, bh = blockIdx.y;
  const int b = bh >> 4, h = bh & 15;
  const int m0 = qt << 6;
  const __bf16* qp = qbuf  + (size_t)bh * TSEQ * HDIM;
  const __bf16* kp = kbuf  + (size_t)bh * TSEQ * HDIM;
  const __bf16* vp = vbufT + (size_t)bh * HDIM * TSEQ;   // [s][t]
  __shared__ __bf16 Qs[8][64][8], Ks[2][8][64][8], Vs[2][8][64][8], Ps[8][64][8];
  __shared__ float wmax[2][64], wsum[2][64];
  const int tid = threadIdx.x, lane = tid & 63, wave = tid >> 6;
  const int wm = (wave >> 1) << 5, wn = (wave & 1) << 5;
  const int lr = lane & 15, kh = lane >> 4;

  auto STAGE_KV = [&](int kt2, int buf) {
    const int n0s = kt2 << 6;
#pragma unroll
    for (int i = 0; i < 2; ++i) {
      const int d = i * 256 + tid;
      const int kb2 = d >> 6, row = d & 63;
      gl_lds16(kp + (size_t)(n0s + row) * HDIM + kb2 * 8, &Ks[buf][kb2][row][0]);
      gl_lds16(vp + (size_t)row * TSEQ + n0s + kb2 * 8, &Vs[buf][kb2][row][0]);
    }
  };

  // stage Q once (2 loads), then KV tile 0 (4 loads)
#pragma unroll
  for (int i = 0; i < 2; ++i) {
    const int d = i * 256 + tid;
    const int kb2 = d >> 6, row = d & 63;
    gl_lds16(qp + (size_t)(m0 + row) * HDIM + kb2 * 8, &Qs[kb2][row][0]);
  }
  STAGE_KV(0, 0);

  float m_[2][4], l_[2][4];
#pragma unroll
  for (int mi = 0; mi < 2; ++mi)
#pragma unroll
    for (int j = 0; j < 4; ++j) { m_[mi][j] = NEGBIG; l_[mi][j] = 0.f; }
  f32x4 o00 = {0,0,0,0}, o01 = {0,0,0,0}, o10 = {0,0,0,0}, o11 = {0,0,0,0};

  int cur = 0;
  for (int kt = 0; kt <= qt; ++kt) {
    const int n0 = kt << 6;
    if (kt < qt) {
      STAGE_KV(kt + 1, cur ^ 1);    // prefetch next tile, stays in flight
      vmwait<4>();                  // Q + tile-kt retired
    } else {
      vmwait<0>();
    }
    __builtin_amdgcn_s_barrier();   // tile kt resident on all waves

    f32x4 s00 = {0,0,0,0}, s01 = {0,0,0,0}, s10 = {0,0,0,0}, s11 = {0,0,0,0};
#pragma unroll
    for (int ks = 0; ks < 2; ++ks) {
      const int kidx = ks * 4 + kh;
      bf16x8 a0 = *(const bf16x8*)&Qs[kidx][wm + lr][0];
      bf16x8 a1 = *(const bf16x8*)&Qs[kidx][wm + 16 + lr][0];
      bf16x8 b0 = *(const bf16x8*)&Ks[cur][kidx][wn + lr][0];
      bf16x8 b1 = *(const bf16x8*)&Ks[cur][kidx][wn + 16 + lr][0];
      s00 = MFMA(a0, b0, s00); s01 = MFMA(a0, b1, s01);
      s10 = MFMA(a1, b0, s10); s11 = MFMA(a1, b1, s11);
    }
    float pv_[2][2][4];
#pragma unroll
    for (int mi = 0; mi < 2; ++mi)
#pragma unroll
      for (int j = 0; j < 4; ++j) {
        const int grow = m0 + wm + mi * 16 + (kh << 2) + j;
        float best = NEGBIG;
#pragma unroll
        for (int ni = 0; ni < 2; ++ni) {
          f32x4 sfr = (mi == 0) ? (ni == 0 ? s00 : s01) : (ni == 0 ? s10 : s11);
          const int gcol = n0 + wn + ni * 16 + lr;
          float t = sfr[j] * SCALEF;
          if (gcol > grow) t = NEGBIG;
          pv_[mi][ni][j] = t;
          best = fmaxf(best, t);
        }
        float v = best;
        v = fmaxf(v, __shfl_xor(v, 1)); v = fmaxf(v, __shfl_xor(v, 2));
        v = fmaxf(v, __shfl_xor(v, 4)); v = fmaxf(v, __shfl_xor(v, 8));
        wmax[wave & 1][wm + mi * 16 + (kh << 2) + j] = v;
      }
    lgkm_barrier();  // B2: wmax visible (vmcnt NOT drained)

    float alpha[2][4];
#pragma unroll
    for (int mi = 0; mi < 2; ++mi)
#pragma unroll
      for (int j = 0; j < 4; ++j) {
        const int rl = wm + mi * 16 + (kh << 2) + j;
        const float tmax = fmaxf(wmax[0][rl], wmax[1][rl]);
        const float mn = fmaxf(m_[mi][j], tmax);
        alpha[mi][j] = __expf(m_[mi][j] - mn);
        m_[mi][j] = mn;
        float rs = 0.f;
#pragma unroll
        for (int ni = 0; ni < 2; ++ni) {
          const float p = __expf(pv_[mi][ni][j] - mn);
          pv_[mi][ni][j] = p;
          rs += p;
        }
        rs += __shfl_xor(rs, 1); rs += __shfl_xor(rs, 2);
        rs += __shfl_xor(rs, 4); rs += __shfl_xor(rs, 8);
        wsum[wave & 1][rl] = rs;
      }
#pragma unroll
    for (int mi = 0; mi < 2; ++mi)
#pragma unroll
      for (int ni = 0; ni < 2; ++ni)
#pragma unroll
        for (int j = 0; j < 4; ++j) {
          const int prow = wm + mi * 16 + (kh << 2) + j;
          const int pcol = wn + ni * 16 + lr;
          Ps[pcol >> 3][prow][pcol & 7] = (__bf16)pv_[mi][ni][j];
        }
    lgkm_barrier();  // B3: wsum & Ps visible (vmcnt NOT drained)

#pragma unroll
    for (int mi = 0; mi < 2; ++mi)
#pragma unroll
      for (int j = 0; j < 4; ++j) {
        const int rl = wm + mi * 16 + (kh << 2) + j;
        l_[mi][j] = l_[mi][j] * alpha[mi][j] + wsum[0][rl] + wsum[1][rl];
      }
#pragma unroll
    for (int j = 0; j < 4; ++j) {
      o00[j] *= alpha[0][j]; o01[j] *= alpha[0][j];
      o10[j] *= alpha[1][j]; o11[j] *= alpha[1][j];
    }
#pragma unroll
    for (int ks = 0; ks < 2; ++ks) {
      const int kidx = ks * 4 + kh;
      bf16x8 a0 = *(const bf16x8*)&Ps[kidx][wm + lr][0];
      bf16x8 a1 = *(const bf16x8*)&Ps[kidx][wm + 16 + lr][0];
      bf16x8 b0 = *(const bf16x8*)&Vs[cur][kidx][wn + lr][0];
      bf16x8 b1 = *(const bf16x8*)&Vs[cur][kidx][wn + 16 + lr][0];
      o00 = MFMA(a0, b0, o00); o01 = MFMA(a0, b1, o01);
      o10 = MFMA(a1, b0, o10); o11 = MFMA(a1, b1, o11);
    }
    __builtin_amdgcn_s_barrier();  // readers of buf done before next overwrite
    cur ^= 1;
  }

#pragma unroll
  for (int mi = 0; mi < 2; ++mi)
#pragma unroll
    for (int ni = 0; ni < 2; ++ni) {
      f32x4 oo = (mi == 0) ? (ni == 0 ? o00 : o01) : (ni == 0 ? o10 : o11);
      const int col = wn + ni * 16 + lr;
#pragma unroll
      for (int j = 0; j < 4; ++j) {
        const int row = m0 + wm + mi * 16 + (kh << 2) + j;
        y2[((size_t)(b * TSEQ) + row) * EDIM + h * HDIM + col] = (__bf16)(oo[j] / l_[mi][j]);
      }
    }
}

// ---------------------------------------------------------------- launcher
extern "C" void kernel_launch(void* const* d_in, const int* in_sizes, int n_in,
                              void* d_out, int out_size, void* d_ws, size_t ws_size,
                              hipStream_t stream) {
  const int*   tokens  = (const int*)d_in[0];
  const float* emb     = (const float*)d_in[1];
  const float* Wqkv    = (const float*)d_in[2];
  const float* bqkv    = (const float*)d_in[3];
  const float* Wo      = (const float*)d_in[4];
  const float* bo      = (const float*)d_in[5];
  const float* W1      = (const float*)d_in[6];
  const float* b1      = (const float*)d_in[7];
  const float* W3      = (const float*)d_in[8];
  const float* b3      = (const float*)d_in[9];
  const float* W2w     = (const float*)d_in[10];
  const float* b2      = (const float*)d_in[11];
  const float* g_mha   = (const float*)d_in[12];
  const float* g_ff    = (const float*)d_in[13];
  const float* g_final = (const float*)d_in[14];
  const float* Wout    = (const float*)d_in[15];
  const float* bout    = (const float*)d_in[16];
  float* out = (float*)d_out;

  char* base = (char*)d_ws;
  size_t off = 0;
  auto alloc = [&](size_t bytes) { char* p = base + off; off = (off + bytes + 255) & ~(size_t)255; return p; };
  float*  x    = (float*)alloc(4u << 20);
  float*  part = (float*)alloc(2048);
  __bf16* ybf  = (__bf16*)alloc(2u << 20);
  __bf16* qbf  = (__bf16*)alloc(2u << 20);
  __bf16* kbf  = (__bf16*)alloc(2u << 20);
  __bf16* vbT  = (__bf16*)alloc(2u << 20);
  __bf16* y2bf = (__bf16*)alloc(2u << 20);
  __bf16* ubf  = (__bf16*)alloc((size_t)MTOK * DPAD * 2);
  float*  pbuf = (float*)alloc((size_t)2 * MTOK * EDIM * 4);
  __bf16* qkvT = (__bf16*)alloc((size_t)3072 * 1024 * 2);
  __bf16* woT  = (__bf16*)alloc((size_t)1024 * 1024 * 2);
  __bf16* w1T  = (__bf16*)alloc((size_t)2752 * 1024 * 2);
  __bf16* w3T  = (__bf16*)alloc((size_t)2752 * 1024 * 2);
  __bf16* w2T  = (__bf16*)alloc((size_t)1024 * 2752 * 2);
  __bf16* WoutT = qkvT;   // alias: spans qkvT..w3T (16.6MB <= 19.5MB), used after last layer

  k_embed<<<MTOK, 256, 0, stream>>>(tokens, emb, x);

  const float* pend_bias = nullptr;   // partials pending fold into x
  for (int l = 0; l < NLAYER; ++l) {
    k_convL<<<3088, 256, 0, stream>>>(
        Wqkv + (size_t)l * EDIM * 3 * EDIM, Wo + (size_t)l * EDIM * EDIM,
        W1 + (size_t)l * EDIM * DFFDIM, W3 + (size_t)l * EDIM * DFFDIM,
        W2w + (size_t)l * DFFDIM * EDIM, qkvT, woT, w1T, w3T, w2T);
    // --- MHA ---
    k_red1f<<<256, 256, 0, stream>>>(x, pend_bias ? pbuf : nullptr,
                                     pbuf + (size_t)MTOK * EDIM, pend_bias, part);
    k_rms2<<<1024, 256, 0, stream>>>(x, g_mha + (size_t)l * EDIM, part, ybf);
    mm<128, 0><<<dim3(48, 8, 1), 256, 0, stream>>>(
        ybf, qkvT, nullptr, bqkv + (size_t)l * 3 * EDIM, nullptr,
        nullptr, nullptr, qbf, kbf, vbT, 3072, 1024, 1024, 1024);
    k_flash<<<dim3(8, 32), 256, 0, stream>>>(qbf, kbf, vbT, y2bf);
    mm<64, 1><<<dim3(16, 16, 2), 256, 0, stream>>>(
        y2bf, woT, nullptr, nullptr, nullptr,
        pbuf, nullptr, nullptr, nullptr, nullptr, 1024, 1024, 1024, 1024);
    // --- SwiGLU FFN ---
    k_red1f<<<256, 256, 0, stream>>>(x, pbuf, pbuf + (size_t)MTOK * EDIM,
                                     bo + (size_t)l * EDIM, part);
    k_rms2<<<1024, 256, 0, stream>>>(x, g_ff + (size_t)l * EDIM, part, ybf);
    mm<128, 2><<<dim3(43, 8, 1), 256, 0, stream>>>(
        ybf, w1T, w3T, b1 + (size_t)l * DFFDIM, b3 + (size_t)l * DFFDIM,
        nullptr, ubf, nullptr, nullptr, nullptr, DFFDIM, 1024, 1024, 1024);
    mm<64, 1><<<dim3(16, 16, 2), 256, 0, stream>>>(
        ubf, w2T, nullptr, nullptr, nullptr,
        pbuf, nullptr, nullptr, nullptr, nullptr, 1024, DPAD, 2752, 2752);
    pend_bias = b2 + (size_t)l * EDIM;
  }

  // --- final RMS + vocab head ---
  k_red1f<<<256, 256, 0, stream>>>(x, pbuf, pbuf + (size_t)MTOK * EDIM, pend_bias, part);
  k_rms2<<<1024, 256, 0, stream>>>(x, g_final, part, ybf);
  k_convH<<<2032, 256, 0, stream>>>(Wout, WoutT);
  mm<128, 3><<<dim3(127, 8, 1), 256, 0, stream>>>(
      ybf, WoutT, nullptr, bout, nullptr,
      out, nullptr, nullptr, nullptr, nullptr, VOCAB, 1024, 1024, 1024);
}